// Round 5
// baseline (506.617 us; speedup 1.0000x reference)
//
#include <hip/hip_runtime.h>
#include <hip/hip_bf16.h>

// Problem constants
#define B   256
#define P   100
#define N1  101
#define E   256
#define HD  256          // H*D
#define H   16
#define D   16
#define NE  8
#define NTOK (B*P)       // 25600
#define NKV  (B*N1)      // 25856

// ---------------------------------------------------------------------------
// Kernel 1: K/V projection. grid (808, 2): y=0 -> K, y=1 -> V.
// Block: 128 threads (2 waves), tile 32 rows x 256 cols.
// Thread = 8 rows x 8 cols (64-reg acc). Weight float4s double-buffered.
// Output layout: (B, H, N1, D).
// ---------------------------------------------------------------------------
__global__ __launch_bounds__(128) void kv_proj_kernel(
    const float* __restrict__ enc, const float* __restrict__ Wk,
    const float* __restrict__ Wv, float* __restrict__ kout,
    float* __restrict__ vout) {
  __shared__ float4 a4[32][64];
  const int tid = threadIdx.x;
  const int row0 = blockIdx.x * 32;
  {
    const float4* src = (const float4*)(enc + (size_t)row0 * E);
    float4* dst = &a4[0][0];
    for (int i = tid; i < 32 * 64; i += 128) dst[i] = src[i];
  }
  const float* __restrict__ W = blockIdx.y ? Wv : Wk;
  float* __restrict__ outp = blockIdx.y ? vout : kout;
  __syncthreads();
  const int rg = tid >> 5;             // 4 rowgroups x 8 rows
  const int r0 = rg * 8;
  const int c0 = (tid & 31) * 8;       // 32 colgroups x 8 cols
  float acc[8][8];
#pragma unroll
  for (int r = 0; r < 8; ++r)
#pragma unroll
    for (int c = 0; c < 8; ++c) acc[r][c] = 0.f;
  float4 wn0[4], wn1[4];
#pragma unroll
  for (int j = 0; j < 4; ++j) {
    wn0[j] = *(const float4*)&W[j * HD + c0];
    wn1[j] = *(const float4*)&W[j * HD + c0 + 4];
  }
  for (int f = 0; f < E; f += 4) {
    float4 w0[4], w1[4];
#pragma unroll
    for (int j = 0; j < 4; ++j) { w0[j] = wn0[j]; w1[j] = wn1[j]; }
    const int fn = (f + 4 < E) ? (f + 4) : 0;
#pragma unroll
    for (int j = 0; j < 4; ++j) {
      wn0[j] = *(const float4*)&W[(fn + j) * HD + c0];
      wn1[j] = *(const float4*)&W[(fn + j) * HD + c0 + 4];
    }
#pragma unroll
    for (int r = 0; r < 8; ++r) {
      float4 xv = a4[r0 + r][f >> 2];
      acc[r][0] += xv.x * w0[0].x + xv.y * w0[1].x + xv.z * w0[2].x + xv.w * w0[3].x;
      acc[r][1] += xv.x * w0[0].y + xv.y * w0[1].y + xv.z * w0[2].y + xv.w * w0[3].y;
      acc[r][2] += xv.x * w0[0].z + xv.y * w0[1].z + xv.z * w0[2].z + xv.w * w0[3].z;
      acc[r][3] += xv.x * w0[0].w + xv.y * w0[1].w + xv.z * w0[2].w + xv.w * w0[3].w;
      acc[r][4] += xv.x * w1[0].x + xv.y * w1[1].x + xv.z * w1[2].x + xv.w * w1[3].x;
      acc[r][5] += xv.x * w1[0].y + xv.y * w1[1].y + xv.z * w1[2].y + xv.w * w1[3].y;
      acc[r][6] += xv.x * w1[0].z + xv.y * w1[1].z + xv.z * w1[2].z + xv.w * w1[3].z;
      acc[r][7] += xv.x * w1[0].w + xv.y * w1[1].w + xv.z * w1[2].w + xv.w * w1[3].w;
    }
  }
  const int hh = c0 >> 4, dd = c0 & 15;   // 8 cols stay within one head
#pragma unroll
  for (int r = 0; r < 8; ++r) {
    int row = row0 + r0 + r;
    int bb = row / N1;
    int nn = row - bb * N1;
    size_t o = (((size_t)bb * H + hh) * N1 + nn) * D + dd;
    float4 t0, t1;
    t0.x = acc[r][0]; t0.y = acc[r][1]; t0.z = acc[r][2]; t0.w = acc[r][3];
    t1.x = acc[r][4]; t1.y = acc[r][5]; t1.z = acc[r][6]; t1.w = acc[r][7];
    *(float4*)&outp[o] = t0;
    *(float4*)&outp[o + 4] = t1;
  }
}

// ---------------------------------------------------------------------------
// Kernel 2: Q projection, K = 260. Same 128-thread 8x8 template.
// Output layout: (B, H, P, D)
// ---------------------------------------------------------------------------
__global__ __launch_bounds__(128) void q_proj_kernel(
    const float* __restrict__ eln, const float* __restrict__ attr,
    const float* __restrict__ Wq, float* __restrict__ qout) {
  __shared__ float a[32][260];
  const int tid = threadIdx.x;
  const int row0 = blockIdx.x * 32;
  {
    const float4* src = (const float4*)(eln + (size_t)row0 * E);
    for (int i = tid; i < 32 * 64; i += 128) {
      int row = i >> 6, c4 = i & 63;
      *(float4*)&a[row][c4 * 4] = src[(size_t)row * 64 + c4];
    }
  }
  {
    int r = tid >> 2, c = tid & 3;
    a[r][E + c] = attr[(size_t)(row0 + r) * 4 + c];
  }
  __syncthreads();
  const int rg = tid >> 5;
  const int r0 = rg * 8;
  const int c0 = (tid & 31) * 8;
  float acc[8][8];
#pragma unroll
  for (int r = 0; r < 8; ++r)
#pragma unroll
    for (int c = 0; c < 8; ++c) acc[r][c] = 0.f;
  float4 wn0[4], wn1[4];
#pragma unroll
  for (int j = 0; j < 4; ++j) {
    wn0[j] = *(const float4*)&Wq[j * HD + c0];
    wn1[j] = *(const float4*)&Wq[j * HD + c0 + 4];
  }
  for (int f = 0; f < 260; f += 4) {
    float4 w0[4], w1[4];
#pragma unroll
    for (int j = 0; j < 4; ++j) { w0[j] = wn0[j]; w1[j] = wn1[j]; }
    const int fn = (f + 4 < 260) ? (f + 4) : 0;
#pragma unroll
    for (int j = 0; j < 4; ++j) {
      wn0[j] = *(const float4*)&Wq[(fn + j) * HD + c0];
      wn1[j] = *(const float4*)&Wq[(fn + j) * HD + c0 + 4];
    }
#pragma unroll
    for (int r = 0; r < 8; ++r) {
      float4 xv = *(const float4*)&a[r0 + r][f];
      acc[r][0] += xv.x * w0[0].x + xv.y * w0[1].x + xv.z * w0[2].x + xv.w * w0[3].x;
      acc[r][1] += xv.x * w0[0].y + xv.y * w0[1].y + xv.z * w0[2].y + xv.w * w0[3].y;
      acc[r][2] += xv.x * w0[0].z + xv.y * w0[1].z + xv.z * w0[2].z + xv.w * w0[3].z;
      acc[r][3] += xv.x * w0[0].w + xv.y * w0[1].w + xv.z * w0[2].w + xv.w * w0[3].w;
      acc[r][4] += xv.x * w1[0].x + xv.y * w1[1].x + xv.z * w1[2].x + xv.w * w1[3].x;
      acc[r][5] += xv.x * w1[0].y + xv.y * w1[1].y + xv.z * w1[2].y + xv.w * w1[3].y;
      acc[r][6] += xv.x * w1[0].z + xv.y * w1[1].z + xv.z * w1[2].z + xv.w * w1[3].z;
      acc[r][7] += xv.x * w1[0].w + xv.y * w1[1].w + xv.z * w1[2].w + xv.w * w1[3].w;
    }
  }
  const int hh = c0 >> 4, dd = c0 & 15;
#pragma unroll
  for (int r = 0; r < 8; ++r) {
    int row = row0 + r0 + r;
    int bb = row / P;
    int pp = row - bb * P;
    size_t o = (((size_t)bb * H + hh) * P + pp) * D + dd;
    float4 t0, t1;
    t0.x = acc[r][0]; t0.y = acc[r][1]; t0.z = acc[r][2]; t0.w = acc[r][3];
    t1.x = acc[r][4]; t1.y = acc[r][5]; t1.z = acc[r][6]; t1.w = acc[r][7];
    *(float4*)&qout[o] = t0;
    *(float4*)&qout[o + 4] = t1;
  }
}

// ---------------------------------------------------------------------------
// Kernel 3: attention. Block = 256 threads = 4 waves = 4 heads of one batch.
// ---------------------------------------------------------------------------
__device__ __forceinline__ float dot16(
    const float4& a0, const float4& a1, const float4& a2, const float4& a3,
    const float4& b0, const float4& b1, const float4& b2, const float4& b3) {
  return a0.x * b0.x + a0.y * b0.y + a0.z * b0.z + a0.w * b0.w +
         a1.x * b1.x + a1.y * b1.y + a1.z * b1.z + a1.w * b1.w +
         a2.x * b2.x + a2.y * b2.y + a2.z * b2.z + a2.w * b2.w +
         a3.x * b3.x + a3.y * b3.y + a3.z * b3.z + a3.w * b3.w;
}

__global__ __launch_bounds__(256) void attn_kernel(
    const float* __restrict__ q, const float* __restrict__ k,
    const float* __restrict__ v, const float* __restrict__ ninf,
    float* __restrict__ x) {
  const int b = blockIdx.x >> 2;
  const int h0 = (blockIdx.x & 3) * 4;
  __shared__ float kl[4 * N1 * D];
  __shared__ float vl[4 * N1 * D];
  const int tid = threadIdx.x;
  {
    const float4* ks = (const float4*)(k + ((size_t)b * H + h0) * N1 * D);
    const float4* vs = (const float4*)(v + ((size_t)b * H + h0) * N1 * D);
    float4* kd = (float4*)kl;
    float4* vd = (float4*)vl;
    for (int i = tid; i < N1 * D; i += 256) { kd[i] = ks[i]; vd[i] = vs[i]; }
  }
  const int w = tid >> 6;
  const int lane = tid & 63;
  const int h = h0 + w;
  const int p0 = lane;
  const bool r1 = (lane + 64 < P);
  const int p1 = r1 ? (lane + 64) : (P - 1);
  const float* qb = q + (((size_t)b * H + h) * P) * D;
  float4 qa0 = *(const float4*)&qb[p0 * D + 0];
  float4 qa1 = *(const float4*)&qb[p0 * D + 4];
  float4 qa2 = *(const float4*)&qb[p0 * D + 8];
  float4 qa3 = *(const float4*)&qb[p0 * D + 12];
  float4 qb0 = *(const float4*)&qb[p1 * D + 0];
  float4 qb1 = *(const float4*)&qb[p1 * D + 4];
  float4 qb2 = *(const float4*)&qb[p1 * D + 8];
  float4 qb3 = *(const float4*)&qb[p1 * D + 12];
  const float* m0 = ninf + ((size_t)b * P + p0) * N1;
  const float* m1 = ninf + ((size_t)b * P + p1) * N1;
  const float* kw = kl + w * N1 * D;
  const float* vw = vl + w * N1 * D;
  __syncthreads();

  float mA = -1e30f, mB = -1e30f, lA = 0.f, lB = 0.f;
  float oA[16], oB[16];
#pragma unroll
  for (int d = 0; d < 16; ++d) { oA[d] = 0.f; oB[d] = 0.f; }
  float4 mk0 = *(const float4*)&m0[0];
  float4 mk1 = *(const float4*)&m1[0];
  const float tm0 = m0[100], tm1 = m1[100];

  for (int it = 0; it < 25; ++it) {
    const int n = it * 4;
    const int nn = (it < 24) ? (n + 4) : 0;
    float4 nx0 = *(const float4*)&m0[nn];
    float4 nx1 = *(const float4*)&m1[nn];
    const float4* kr0 = (const float4*)&kw[(n + 0) * D];
    const float4* kr1 = (const float4*)&kw[(n + 1) * D];
    const float4* kr2 = (const float4*)&kw[(n + 2) * D];
    const float4* kr3 = (const float4*)&kw[(n + 3) * D];
    float4 k00 = kr0[0], k01 = kr0[1], k02 = kr0[2], k03 = kr0[3];
    float4 k10 = kr1[0], k11 = kr1[1], k12 = kr1[2], k13 = kr1[3];
    float4 k20 = kr2[0], k21 = kr2[1], k22 = kr2[2], k23 = kr2[3];
    float4 k30 = kr3[0], k31 = kr3[1], k32 = kr3[2], k33 = kr3[3];
    float sA0 = dot16(qa0, qa1, qa2, qa3, k00, k01, k02, k03) * 0.25f + mk0.x;
    float sA1 = dot16(qa0, qa1, qa2, qa3, k10, k11, k12, k13) * 0.25f + mk0.y;
    float sA2 = dot16(qa0, qa1, qa2, qa3, k20, k21, k22, k23) * 0.25f + mk0.z;
    float sA3 = dot16(qa0, qa1, qa2, qa3, k30, k31, k32, k33) * 0.25f + mk0.w;
    float sB0 = dot16(qb0, qb1, qb2, qb3, k00, k01, k02, k03) * 0.25f + mk1.x;
    float sB1 = dot16(qb0, qb1, qb2, qb3, k10, k11, k12, k13) * 0.25f + mk1.y;
    float sB2 = dot16(qb0, qb1, qb2, qb3, k20, k21, k22, k23) * 0.25f + mk1.z;
    float sB3 = dot16(qb0, qb1, qb2, qb3, k30, k31, k32, k33) * 0.25f + mk1.w;
    float mnA = fmaxf(fmaxf(fmaxf(sA0, sA1), fmaxf(sA2, sA3)), mA);
    float mnB = fmaxf(fmaxf(fmaxf(sB0, sB1), fmaxf(sB2, sB3)), mB);
    float scA = __expf(mA - mnA);
    float scB = __expf(mB - mnB);
    float pA0 = __expf(sA0 - mnA), pA1 = __expf(sA1 - mnA);
    float pA2 = __expf(sA2 - mnA), pA3 = __expf(sA3 - mnA);
    float pB0 = __expf(sB0 - mnB), pB1 = __expf(sB1 - mnB);
    float pB2 = __expf(sB2 - mnB), pB3 = __expf(sB3 - mnB);
    lA = lA * scA + (pA0 + pA1) + (pA2 + pA3);
    lB = lB * scB + (pB0 + pB1) + (pB2 + pB3);
    const float4* vr0 = (const float4*)&vw[(n + 0) * D];
    const float4* vr1 = (const float4*)&vw[(n + 1) * D];
    const float4* vr2 = (const float4*)&vw[(n + 2) * D];
    const float4* vr3 = (const float4*)&vw[(n + 3) * D];
#pragma unroll
    for (int dq = 0; dq < 4; ++dq) {
      float4 v0 = vr0[dq], v1 = vr1[dq], v2 = vr2[dq], v3 = vr3[dq];
      oA[4 * dq + 0] = oA[4 * dq + 0] * scA + pA0 * v0.x + pA1 * v1.x + pA2 * v2.x + pA3 * v3.x;
      oA[4 * dq + 1] = oA[4 * dq + 1] * scA + pA0 * v0.y + pA1 * v1.y + pA2 * v2.y + pA3 * v3.y;
      oA[4 * dq + 2] = oA[4 * dq + 2] * scA + pA0 * v0.z + pA1 * v1.z + pA2 * v2.z + pA3 * v3.z;
      oA[4 * dq + 3] = oA[4 * dq + 3] * scA + pA0 * v0.w + pA1 * v1.w + pA2 * v2.w + pA3 * v3.w;
      oB[4 * dq + 0] = oB[4 * dq + 0] * scB + pB0 * v0.x + pB1 * v1.x + pB2 * v2.x + pB3 * v3.x;
      oB[4 * dq + 1] = oB[4 * dq + 1] * scB + pB0 * v0.y + pB1 * v1.y + pB2 * v2.y + pB3 * v3.y;
      oB[4 * dq + 2] = oB[4 * dq + 2] * scB + pB0 * v0.z + pB1 * v1.z + pB2 * v2.z + pB3 * v3.z;
      oB[4 * dq + 3] = oB[4 * dq + 3] * scB + pB0 * v0.w + pB1 * v1.w + pB2 * v2.w + pB3 * v3.w;
    }
    mA = mnA; mB = mnB;
    mk0 = nx0; mk1 = nx1;
  }
  {
    const float4* kr = (const float4*)&kw[100 * D];
    float4 k0 = kr[0], k1 = kr[1], k2 = kr[2], k3 = kr[3];
    float sA = dot16(qa0, qa1, qa2, qa3, k0, k1, k2, k3) * 0.25f + tm0;
    float sB = dot16(qb0, qb1, qb2, qb3, k0, k1, k2, k3) * 0.25f + tm1;
    float mnA = fmaxf(mA, sA), mnB = fmaxf(mB, sB);
    float scA = __expf(mA - mnA), scB = __expf(mB - mnB);
    float pA = __expf(sA - mnA), pB = __expf(sB - mnB);
    lA = lA * scA + pA;
    lB = lB * scB + pB;
    const float4* vr = (const float4*)&vw[100 * D];
#pragma unroll
    for (int dq = 0; dq < 4; ++dq) {
      float4 v0 = vr[dq];
      oA[4 * dq + 0] = oA[4 * dq + 0] * scA + pA * v0.x;
      oA[4 * dq + 1] = oA[4 * dq + 1] * scA + pA * v0.y;
      oA[4 * dq + 2] = oA[4 * dq + 2] * scA + pA * v0.z;
      oA[4 * dq + 3] = oA[4 * dq + 3] * scA + pA * v0.w;
      oB[4 * dq + 0] = oB[4 * dq + 0] * scB + pB * v0.x;
      oB[4 * dq + 1] = oB[4 * dq + 1] * scB + pB * v0.y;
      oB[4 * dq + 2] = oB[4 * dq + 2] * scB + pB * v0.z;
      oB[4 * dq + 3] = oB[4 * dq + 3] * scB + pB * v0.w;
    }
  }
  const float invA = 1.f / lA;
  float* xr0 = &x[((size_t)b * P + p0) * HD + h * D];
#pragma unroll
  for (int dq = 0; dq < 4; ++dq) {
    float4 t;
    t.x = oA[4 * dq + 0] * invA; t.y = oA[4 * dq + 1] * invA;
    t.z = oA[4 * dq + 2] * invA; t.w = oA[4 * dq + 3] * invA;
    *(float4*)&xr0[4 * dq] = t;
  }
  if (r1) {
    const float invB = 1.f / lB;
    float* xr1 = &x[((size_t)b * P + p1) * HD + h * D];
#pragma unroll
    for (int dq = 0; dq < 4; ++dq) {
      float4 t;
      t.x = oB[4 * dq + 0] * invB; t.y = oB[4 * dq + 1] * invB;
      t.z = oB[4 * dq + 2] * invB; t.w = oB[4 * dq + 3] * invB;
      *(float4*)&xr1[4 * dq] = t;
    }
  }
}

// ---------------------------------------------------------------------------
// Kernel 4: router logits (fp32, deterministic) + top2 + gates. UNCHANGED.
// ---------------------------------------------------------------------------
__global__ __launch_bounds__(256) void logits_top2_kernel(
    const float* __restrict__ x, const float* __restrict__ Wg,
    int* __restrict__ topi, float* __restrict__ topg) {
  __shared__ float xl[32][260];
  __shared__ float wg[E * NE];
  __shared__ float lg[32][9];
  const int tid = threadIdx.x;
  const int t0 = blockIdx.x * 32;
  for (int r = 0; r < 32; ++r) xl[r][tid] = x[(size_t)(t0 + r) * HD + tid];
  for (int i = tid; i < E * NE; i += 256) wg[i] = Wg[i];
  __syncthreads();
  const int r = tid >> 3, e = tid & 7;
  float acc = 0.f;
  for (int f = 0; f < E; ++f) acc += xl[r][f] * wg[f * NE + e];
  lg[r][e] = acc;
  __syncthreads();
  if (tid < 32) {
    float v[8];
#pragma unroll
    for (int j = 0; j < 8; ++j) v[j] = lg[tid][j];
    int i1 = 0; float v1 = v[0];
#pragma unroll
    for (int j = 1; j < 8; ++j) if (v[j] > v1) { v1 = v[j]; i1 = j; }
    int i2 = -1; float v2 = -1e30f;
#pragma unroll
    for (int j = 0; j < 8; ++j)
      if (j != i1 && v[j] > v2) { v2 = v[j]; i2 = j; }
    float ex = __expf(v2 - v1);
    float g1 = 1.f / (1.f + ex);
    float g2 = ex / (1.f + ex);
    int t = t0 + tid;
    topi[t * 2 + 0] = i1; topi[t * 2 + 1] = i2;
    topg[t * 2 + 0] = g1; topg[t * 2 + 1] = g2;
  }
}

// ---------------------------------------------------------------------------
// Kernel 5: build per-expert token lists. UNCHANGED.
// ---------------------------------------------------------------------------
__global__ __launch_bounds__(1024) void build_lists_kernel(
    const int* __restrict__ topi, const float* __restrict__ topg,
    int* __restrict__ list_tok, float* __restrict__ list_gate,
    int* __restrict__ counts) {
  const int e = blockIdx.x;
  const int tid = threadIdx.x;
  const int lane = tid & 63, w = tid >> 6;
  __shared__ int wsum[16];
  int running = 0;
  for (int c = 0; c < NTOK; c += 1024) {
    int t = c + tid;
    int ia = topi[t * 2 + 0], ib = topi[t * 2 + 1];
    int slot = (ia == e) ? 0 : ((ib == e) ? 1 : -1);
    int f = (slot >= 0) ? 1 : 0;
    unsigned long long m = __ballot(f);
    if (lane == 0) wsum[w] = __popcll(m);
    __syncthreads();
    int wbase = 0, total = 0;
#pragma unroll
    for (int i = 0; i < 16; ++i) {
      int s = wsum[i];
      if (i < w) wbase += s;
      total += s;
    }
    if (f) {
      int prefix = __popcll(m & ((1ull << lane) - 1ull));
      int pos = running + wbase + prefix;
      list_tok[e * NTOK + pos] = (t << 1) | slot;
      list_gate[e * NTOK + pos] = topg[t * 2 + slot];
    }
    running += total;
    __syncthreads();
  }
  if (tid == 0) counts[e] = running;
}

// ---------------------------------------------------------------------------
// Kernel 6: sparse expert GEMM. Flattened tile grid (in-kernel prefix scan
// over counts). Block 128 threads, tile 32 tokens x 256 cols, thread 8x8.
// ---------------------------------------------------------------------------
__global__ __launch_bounds__(128) void expert_gemm_kernel(
    const float* __restrict__ x, const float* __restrict__ eW,
    const float* __restrict__ eb, const int* __restrict__ list_tok,
    const float* __restrict__ list_gate, const int* __restrict__ counts,
    float* __restrict__ p0, float* __restrict__ p1) {
  // locate (expert, tile) for this block
  int e = 0, t0 = -1;
  {
    int rem = blockIdx.x;
    for (int i = 0; i < NE; ++i) {
      int nt = (counts[i] + 31) >> 5;
      if (rem < nt) { e = i; t0 = rem * 32; break; }
      rem -= nt;
    }
  }
  if (t0 < 0) return;
  const int cnt = counts[e];
  const int nr = min(32, cnt - t0);
  __shared__ float4 xl4[32][64];
  __shared__ int stok[32];
  __shared__ float sg[32];
  const int tid = threadIdx.x;
  if (tid < 32) {
    int src = e * NTOK + t0 + ((tid < nr) ? tid : 0);
    stok[tid] = list_tok[src];
    sg[tid] = (tid < nr) ? list_gate[e * NTOK + t0 + tid] : 0.f;
  }
  __syncthreads();
  for (int i = tid; i < 32 * 64; i += 128) {
    int r = i >> 6, c4 = i & 63;
    xl4[r][c4] = *(const float4*)&x[(size_t)(stok[r] >> 1) * HD + c4 * 4];
  }
  __syncthreads();
  const int rg = tid >> 5;
  const int r0 = rg * 8;
  const int c0 = (tid & 31) * 8;
  float acc[8][8];
#pragma unroll
  for (int r = 0; r < 8; ++r)
#pragma unroll
    for (int c = 0; c < 8; ++c) acc[r][c] = 0.f;
  const float* W = eW + (size_t)e * HD * E;
  float4 wn0[4], wn1[4];
#pragma unroll
  for (int j = 0; j < 4; ++j) {
    wn0[j] = *(const float4*)&W[j * E + c0];
    wn1[j] = *(const float4*)&W[j * E + c0 + 4];
  }
  for (int f = 0; f < HD; f += 4) {
    float4 w0[4], w1[4];
#pragma unroll
    for (int j = 0; j < 4; ++j) { w0[j] = wn0[j]; w1[j] = wn1[j]; }
    const int fn = (f + 4 < HD) ? (f + 4) : 0;
#pragma unroll
    for (int j = 0; j < 4; ++j) {
      wn0[j] = *(const float4*)&W[(fn + j) * E + c0];
      wn1[j] = *(const float4*)&W[(fn + j) * E + c0 + 4];
    }
#pragma unroll
    for (int r = 0; r < 8; ++r) {
      float4 xv = xl4[r0 + r][f >> 2];
      acc[r][0] += xv.x * w0[0].x + xv.y * w0[1].x + xv.z * w0[2].x + xv.w * w0[3].x;
      acc[r][1] += xv.x * w0[0].y + xv.y * w0[1].y + xv.z * w0[2].y + xv.w * w0[3].y;
      acc[r][2] += xv.x * w0[0].z + xv.y * w0[1].z + xv.z * w0[2].z + xv.w * w0[3].z;
      acc[r][3] += xv.x * w0[0].w + xv.y * w0[1].w + xv.z * w0[2].w + xv.w * w0[3].w;
      acc[r][4] += xv.x * w1[0].x + xv.y * w1[1].x + xv.z * w1[2].x + xv.w * w1[3].x;
      acc[r][5] += xv.x * w1[0].y + xv.y * w1[1].y + xv.z * w1[2].y + xv.w * w1[3].y;
      acc[r][6] += xv.x * w1[0].z + xv.y * w1[1].z + xv.z * w1[2].z + xv.w * w1[3].z;
      acc[r][7] += xv.x * w1[0].w + xv.y * w1[1].w + xv.z * w1[2].w + xv.w * w1[3].w;
    }
  }
  float bias[8];
  {
    float4 b0 = *(const float4*)&eb[e * E + c0];
    float4 b1 = *(const float4*)&eb[e * E + c0 + 4];
    bias[0] = b0.x; bias[1] = b0.y; bias[2] = b0.z; bias[3] = b0.w;
    bias[4] = b1.x; bias[5] = b1.y; bias[6] = b1.z; bias[7] = b1.w;
  }
#pragma unroll
  for (int r = 0; r < 8; ++r) {
    if (r0 + r < nr) {
      int tokw = stok[r0 + r];
      int tok = tokw >> 1;
      int slot = tokw & 1;
      float g = sg[r0 + r];
      float* dst = (slot ? p1 : p0) + (size_t)tok * E + c0;
      float4 t0v, t1v;
      t0v.x = g * (acc[r][0] + bias[0]); t0v.y = g * (acc[r][1] + bias[1]);
      t0v.z = g * (acc[r][2] + bias[2]); t0v.w = g * (acc[r][3] + bias[3]);
      t1v.x = g * (acc[r][4] + bias[4]); t1v.y = g * (acc[r][5] + bias[5]);
      t1v.z = g * (acc[r][6] + bias[6]); t1v.w = g * (acc[r][7] + bias[7]);
      *(float4*)&dst[0] = t0v;
      *(float4*)&dst[4] = t1v;
    }
  }
}

// ---------------------------------------------------------------------------
// Kernel 7: score2 = mh @ enc^T, per batch. grid (4, 256), block 128.
// ---------------------------------------------------------------------------
__global__ __launch_bounds__(128) void score2_kernel(
    const float* __restrict__ p0, const float* __restrict__ p1,
    const float* __restrict__ enc, float* __restrict__ out) {
  const int b = blockIdx.y;
  const int pt = blockIdx.x * 25;
  __shared__ float mh[25][E];
  const int tid = threadIdx.x;
  for (int i = tid; i < 25 * E; i += 128) {
    int r = i >> 8, c = i & 255;
    int t = b * P + pt + r;
    mh[r][c] = p0[(size_t)t * E + c] + p1[(size_t)t * E + c];
  }
  __syncthreads();
  const int n = tid;
  if (n >= N1) return;
  float acc[25];
#pragma unroll
  for (int r = 0; r < 25; ++r) acc[r] = 0.f;
  const float* er = enc + ((size_t)b * N1 + n) * E;
  for (int ee = 0; ee < E; ee += 4) {
    float4 ev = *(const float4*)&er[ee];
#pragma unroll
    for (int r = 0; r < 25; ++r) {
      float4 mv = *(const float4*)&mh[r][ee];
      acc[r] += mv.x * ev.x + mv.y * ev.y + mv.z * ev.z + mv.w * ev.w;
    }
  }
#pragma unroll
  for (int r = 0; r < 25; ++r) out[((size_t)b * P + pt + r) * N1 + n] = acc[r];
}

// ---------------------------------------------------------------------------
// Kernel 8: add biases, tanh clip, + ninf, row softmax.  In-place on d_out.
// ---------------------------------------------------------------------------
__global__ __launch_bounds__(256) void softmax2_kernel(
    float* __restrict__ sc, const float* __restrict__ ab,
    const float* __restrict__ ab1, const float* __restrict__ ninf) {
  const int row = blockIdx.x * 4 + (threadIdx.x >> 6);
  const int lane = threadIdx.x & 63;
  float* srow = sc + (size_t)row * N1;
  const float* a = ab + (size_t)row * N1;
  const float* a1 = ab1 + (size_t)row * N1;
  const float* nf = ninf + (size_t)row * N1;
  float s0 = -1e30f, s1 = -1e30f;
  {
    int i = lane;
    float s = srow[i] + a[i] + a1[i];
    float e2 = __expf(s * 0.125f);
    float th = 1.f - 2.f / (e2 + 1.f);
    s0 = 10.f * th + nf[i];
  }
  if (lane < N1 - 64) {
    int i = lane + 64;
    float s = srow[i] + a[i] + a1[i];
    float e2 = __expf(s * 0.125f);
    float th = 1.f - 2.f / (e2 + 1.f);
    s1 = 10.f * th + nf[i];
  }
  float mx = fmaxf(s0, s1);
#pragma unroll
  for (int off = 32; off > 0; off >>= 1) mx = fmaxf(mx, __shfl_xor(mx, off, 64));
  float p0 = __expf(s0 - mx);
  float p1 = (lane < N1 - 64) ? __expf(s1 - mx) : 0.f;
  float sum = p0 + p1;
#pragma unroll
  for (int off = 32; off > 0; off >>= 1) sum += __shfl_xor(sum, off, 64);
  float inv = 1.f / sum;
  srow[lane] = p0 * inv;
  if (lane < N1 - 64) srow[lane + 64] = p1 * inv;
}

// ---------------------------------------------------------------------------
extern "C" void kernel_launch(void* const* d_in, const int* in_sizes, int n_in,
                              void* d_out, int out_size, void* d_ws,
                              size_t ws_size, hipStream_t stream) {
  const float* eln  = (const float*)d_in[0];
  const float* attr = (const float*)d_in[1];
  const float* enc  = (const float*)d_in[2];
  const float* ninf = (const float*)d_in[3];
  const float* ab   = (const float*)d_in[4];
  const float* ab1  = (const float*)d_in[5];
  const float* Wq   = (const float*)d_in[6];
  const float* Wk   = (const float*)d_in[7];
  const float* Wv   = (const float*)d_in[8];
  const float* Wg   = (const float*)d_in[9];
  const float* eW   = (const float*)d_in[10];
  const float* eb   = (const float*)d_in[11];
  float* out = (float*)d_out;

  char* ws = (char*)d_ws;
  size_t off = 0;
  auto carve = [&](size_t bytes) {
    char* p = ws + off;
    off += (bytes + 255) & ~size_t(255);
    return p;
  };
  float* kbuf = (float*)carve(sizeof(float) * NKV * HD);
  float* vbuf = (float*)carve(sizeof(float) * NKV * HD);
  float* qbuf = (float*)carve(sizeof(float) * NTOK * HD);
  float* xbuf = (float*)carve(sizeof(float) * NTOK * HD);
  int*   topi = (int*)carve(sizeof(int) * NTOK * 2);
  float* topg = (float*)carve(sizeof(float) * NTOK * 2);
  int*   counts = (int*)carve(sizeof(int) * 16);
  int*   list_tok = (int*)carve(sizeof(int) * NE * NTOK);
  float* list_gate = (float*)carve(sizeof(float) * NE * NTOK);
  // p0/p1 alias k/v buffers (dead after attention)
  float* pp0 = kbuf;
  float* pp1 = vbuf;

  dim3 kvg(NKV / 32, 2);
  kv_proj_kernel<<<kvg, 128, 0, stream>>>(enc, Wk, Wv, kbuf, vbuf);
  q_proj_kernel<<<NTOK / 32, 128, 0, stream>>>(eln, attr, Wq, qbuf);
  attn_kernel<<<B * 4, 256, 0, stream>>>(qbuf, kbuf, vbuf, ninf, xbuf);
  logits_top2_kernel<<<NTOK / 32, 256, 0, stream>>>(xbuf, Wg, topi, topg);
  build_lists_kernel<<<NE, 1024, 0, stream>>>(topi, topg, list_tok, list_gate,
                                              counts);
  // max tiles = NE + (2*NTOK)/32 = 8 + 1600 = 1608
  expert_gemm_kernel<<<1608, 128, 0, stream>>>(xbuf, eW, eb, list_tok,
                                               list_gate, counts, pp0, pp1);
  dim3 s2(4, B);
  score2_kernel<<<s2, 128, 0, stream>>>(pp0, pp1, enc, out);
  softmax2_kernel<<<NTOK / 4, 256, 0, stream>>>(out, ab, ab1, ninf);
}

// Round 6
// 403.883 us; speedup vs baseline: 1.2544x; 1.2544x over previous
//
#include <hip/hip_runtime.h>
#include <hip/hip_bf16.h>

// Problem constants
#define B   256
#define P   100
#define N1  101
#define E   256
#define HD  256          // H*D
#define H   16
#define D   16
#define NE  8
#define NTOK (B*P)       // 25600
#define NKV  (B*N1)      // 25856

typedef __attribute__((ext_vector_type(8))) short short8;
typedef __attribute__((ext_vector_type(4))) float f32x4;
typedef unsigned short ushort_t;

__device__ __forceinline__ unsigned short f2bf(float f) {
  unsigned int u = __float_as_uint(f);
  unsigned int r = (u + 0x7fffu + ((u >> 16) & 1u)) >> 16;
  return (unsigned short)r;
}
__device__ __forceinline__ float bf2f(unsigned short b) {
  return __uint_as_float(((unsigned int)b) << 16);
}

// ---------------------------------------------------------------------------
// Kernel 1: K/V projection. grid (808, 2): y=0 -> K, y=1 -> V.
// 256 threads, tile 32 rows x 256 cols, thread = 8 rows x 4 cols, prefetch.
// Output layout: (B, H, N1, D).   [round-4 proven shape]
// ---------------------------------------------------------------------------
__global__ __launch_bounds__(256) void kv_proj_kernel(
    const float* __restrict__ enc, const float* __restrict__ Wk,
    const float* __restrict__ Wv, float* __restrict__ kout,
    float* __restrict__ vout) {
  __shared__ float a[32][E];
  const int tid = threadIdx.x;
  const int row0 = blockIdx.x * 32;
  {
    const float4* src = (const float4*)(enc + (size_t)row0 * E);
    float4* dst = (float4*)&a[0][0];
    for (int i = tid; i < 32 * 64; i += 256) dst[i] = src[i];
  }
  const float* __restrict__ W = blockIdx.y ? Wv : Wk;
  float* __restrict__ outp = blockIdx.y ? vout : kout;
  __syncthreads();
  const int rg = tid >> 6;             // 4 rowgroups x 8 rows
  const int c0 = (tid & 63) * 4;       // 64 colgroups x 4 cols
  float acc[8][4];
#pragma unroll
  for (int r = 0; r < 8; ++r)
#pragma unroll
    for (int c = 0; c < 4; ++c) acc[r][c] = 0.f;
  float4 wn[4];
#pragma unroll
  for (int j = 0; j < 4; ++j) wn[j] = *(const float4*)&W[j * HD + c0];
  for (int f = 0; f < E; f += 4) {
    float4 wc[4];
#pragma unroll
    for (int j = 0; j < 4; ++j) wc[j] = wn[j];
    const int fn = (f + 4 < E) ? (f + 4) : 0;
#pragma unroll
    for (int j = 0; j < 4; ++j) wn[j] = *(const float4*)&W[(fn + j) * HD + c0];
#pragma unroll
    for (int r = 0; r < 8; ++r) {
      float4 xv = *(const float4*)&a[rg * 8 + r][f];
      acc[r][0] += xv.x * wc[0].x + xv.y * wc[1].x + xv.z * wc[2].x + xv.w * wc[3].x;
      acc[r][1] += xv.x * wc[0].y + xv.y * wc[1].y + xv.z * wc[2].y + xv.w * wc[3].y;
      acc[r][2] += xv.x * wc[0].z + xv.y * wc[1].z + xv.z * wc[2].z + xv.w * wc[3].z;
      acc[r][3] += xv.x * wc[0].w + xv.y * wc[1].w + xv.z * wc[2].w + xv.w * wc[3].w;
    }
  }
  const int hh = c0 >> 4, dd = c0 & 15;
#pragma unroll
  for (int r = 0; r < 8; ++r) {
    int row = row0 + rg * 8 + r;
    int bb = row / N1;
    int nn = row - bb * N1;
    size_t o = (((size_t)bb * H + hh) * N1 + nn) * D + dd;
    float4 t;
    t.x = acc[r][0]; t.y = acc[r][1]; t.z = acc[r][2]; t.w = acc[r][3];
    *(float4*)&outp[o] = t;
  }
}

// ---------------------------------------------------------------------------
// Kernel 2: Q projection, K = 260. 256 threads, 8 rows x 4 cols, prefetch.
// Output layout: (B, H, P, D)     [round-4 proven shape]
// ---------------------------------------------------------------------------
__global__ __launch_bounds__(256) void q_proj_kernel(
    const float* __restrict__ eln, const float* __restrict__ attr,
    const float* __restrict__ Wq, float* __restrict__ qout) {
  __shared__ float a[32][260];
  const int tid = threadIdx.x;
  const int row0 = blockIdx.x * 32;
  for (int r = 0; r < 32; ++r) a[r][tid] = eln[(size_t)(row0 + r) * E + tid];
  if (tid < 128) {
    int r = tid >> 2, c = tid & 3;
    a[r][E + c] = attr[(size_t)(row0 + r) * 4 + c];
  }
  __syncthreads();
  const int rg = tid >> 6;
  const int c0 = (tid & 63) * 4;
  float acc[8][4];
#pragma unroll
  for (int r = 0; r < 8; ++r)
#pragma unroll
    for (int c = 0; c < 4; ++c) acc[r][c] = 0.f;
  float4 wn[4];
#pragma unroll
  for (int j = 0; j < 4; ++j) wn[j] = *(const float4*)&Wq[j * HD + c0];
  for (int f = 0; f < 260; f += 4) {
    float4 wc[4];
#pragma unroll
    for (int j = 0; j < 4; ++j) wc[j] = wn[j];
    const int fn = (f + 4 < 260) ? (f + 4) : 0;
#pragma unroll
    for (int j = 0; j < 4; ++j) wn[j] = *(const float4*)&Wq[(fn + j) * HD + c0];
#pragma unroll
    for (int r = 0; r < 8; ++r) {
      float4 xv = *(const float4*)&a[rg * 8 + r][f];
      acc[r][0] += xv.x * wc[0].x + xv.y * wc[1].x + xv.z * wc[2].x + xv.w * wc[3].x;
      acc[r][1] += xv.x * wc[0].y + xv.y * wc[1].y + xv.z * wc[2].y + xv.w * wc[3].y;
      acc[r][2] += xv.x * wc[0].z + xv.y * wc[1].z + xv.z * wc[2].z + xv.w * wc[3].z;
      acc[r][3] += xv.x * wc[0].w + xv.y * wc[1].w + xv.z * wc[2].w + xv.w * wc[3].w;
    }
  }
  const int hh = c0 >> 4, dd = c0 & 15;
#pragma unroll
  for (int r = 0; r < 8; ++r) {
    int row = row0 + rg * 8 + r;
    int bb = row / P;
    int pp = row - bb * P;
    size_t o = (((size_t)bb * H + hh) * P + pp) * D + dd;
    float4 t;
    t.x = acc[r][0]; t.y = acc[r][1]; t.z = acc[r][2]; t.w = acc[r][3];
    *(float4*)&qout[o] = t;
  }
}

// ---------------------------------------------------------------------------
// Kernel 3: attention. Block = 256 threads = 4 waves = 4 heads of one batch.
// ---------------------------------------------------------------------------
__device__ __forceinline__ float dot16(
    const float4& a0, const float4& a1, const float4& a2, const float4& a3,
    const float4& b0, const float4& b1, const float4& b2, const float4& b3) {
  return a0.x * b0.x + a0.y * b0.y + a0.z * b0.z + a0.w * b0.w +
         a1.x * b1.x + a1.y * b1.y + a1.z * b1.z + a1.w * b1.w +
         a2.x * b2.x + a2.y * b2.y + a2.z * b2.z + a2.w * b2.w +
         a3.x * b3.x + a3.y * b3.y + a3.z * b3.z + a3.w * b3.w;
}

__global__ __launch_bounds__(256) void attn_kernel(
    const float* __restrict__ q, const float* __restrict__ k,
    const float* __restrict__ v, const float* __restrict__ ninf,
    float* __restrict__ x) {
  const int b = blockIdx.x >> 2;
  const int h0 = (blockIdx.x & 3) * 4;
  __shared__ float kl[4 * N1 * D];
  __shared__ float vl[4 * N1 * D];
  const int tid = threadIdx.x;
  {
    const float4* ks = (const float4*)(k + ((size_t)b * H + h0) * N1 * D);
    const float4* vs = (const float4*)(v + ((size_t)b * H + h0) * N1 * D);
    float4* kd = (float4*)kl;
    float4* vd = (float4*)vl;
    for (int i = tid; i < N1 * D; i += 256) { kd[i] = ks[i]; vd[i] = vs[i]; }
  }
  const int w = tid >> 6;
  const int lane = tid & 63;
  const int h = h0 + w;
  const int p0 = lane;
  const bool r1 = (lane + 64 < P);
  const int p1 = r1 ? (lane + 64) : (P - 1);
  const float* qb = q + (((size_t)b * H + h) * P) * D;
  float4 qa0 = *(const float4*)&qb[p0 * D + 0];
  float4 qa1 = *(const float4*)&qb[p0 * D + 4];
  float4 qa2 = *(const float4*)&qb[p0 * D + 8];
  float4 qa3 = *(const float4*)&qb[p0 * D + 12];
  float4 qb0 = *(const float4*)&qb[p1 * D + 0];
  float4 qb1 = *(const float4*)&qb[p1 * D + 4];
  float4 qb2 = *(const float4*)&qb[p1 * D + 8];
  float4 qb3 = *(const float4*)&qb[p1 * D + 12];
  const float* m0 = ninf + ((size_t)b * P + p0) * N1;
  const float* m1 = ninf + ((size_t)b * P + p1) * N1;
  const float* kw = kl + w * N1 * D;
  const float* vw = vl + w * N1 * D;
  __syncthreads();

  float mA = -1e30f, mB = -1e30f, lA = 0.f, lB = 0.f;
  float oA[16], oB[16];
#pragma unroll
  for (int d = 0; d < 16; ++d) { oA[d] = 0.f; oB[d] = 0.f; }
  float4 mk0 = *(const float4*)&m0[0];
  float4 mk1 = *(const float4*)&m1[0];
  const float tm0 = m0[100], tm1 = m1[100];

  for (int it = 0; it < 25; ++it) {
    const int n = it * 4;
    const int nn = (it < 24) ? (n + 4) : 0;
    float4 nx0 = *(const float4*)&m0[nn];
    float4 nx1 = *(const float4*)&m1[nn];
    const float4* kr0 = (const float4*)&kw[(n + 0) * D];
    const float4* kr1 = (const float4*)&kw[(n + 1) * D];
    const float4* kr2 = (const float4*)&kw[(n + 2) * D];
    const float4* kr3 = (const float4*)&kw[(n + 3) * D];
    float4 k00 = kr0[0], k01 = kr0[1], k02 = kr0[2], k03 = kr0[3];
    float4 k10 = kr1[0], k11 = kr1[1], k12 = kr1[2], k13 = kr1[3];
    float4 k20 = kr2[0], k21 = kr2[1], k22 = kr2[2], k23 = kr2[3];
    float4 k30 = kr3[0], k31 = kr3[1], k32 = kr3[2], k33 = kr3[3];
    float sA0 = dot16(qa0, qa1, qa2, qa3, k00, k01, k02, k03) * 0.25f + mk0.x;
    float sA1 = dot16(qa0, qa1, qa2, qa3, k10, k11, k12, k13) * 0.25f + mk0.y;
    float sA2 = dot16(qa0, qa1, qa2, qa3, k20, k21, k22, k23) * 0.25f + mk0.z;
    float sA3 = dot16(qa0, qa1, qa2, qa3, k30, k31, k32, k33) * 0.25f + mk0.w;
    float sB0 = dot16(qb0, qb1, qb2, qb3, k00, k01, k02, k03) * 0.25f + mk1.x;
    float sB1 = dot16(qb0, qb1, qb2, qb3, k10, k11, k12, k13) * 0.25f + mk1.y;
    float sB2 = dot16(qb0, qb1, qb2, qb3, k20, k21, k22, k23) * 0.25f + mk1.z;
    float sB3 = dot16(qb0, qb1, qb2, qb3, k30, k31, k32, k33) * 0.25f + mk1.w;
    float mnA = fmaxf(fmaxf(fmaxf(sA0, sA1), fmaxf(sA2, sA3)), mA);
    float mnB = fmaxf(fmaxf(fmaxf(sB0, sB1), fmaxf(sB2, sB3)), mB);
    float scA = __expf(mA - mnA);
    float scB = __expf(mB - mnB);
    float pA0 = __expf(sA0 - mnA), pA1 = __expf(sA1 - mnA);
    float pA2 = __expf(sA2 - mnA), pA3 = __expf(sA3 - mnA);
    float pB0 = __expf(sB0 - mnB), pB1 = __expf(sB1 - mnB);
    float pB2 = __expf(sB2 - mnB), pB3 = __expf(sB3 - mnB);
    lA = lA * scA + (pA0 + pA1) + (pA2 + pA3);
    lB = lB * scB + (pB0 + pB1) + (pB2 + pB3);
    const float4* vr0 = (const float4*)&vw[(n + 0) * D];
    const float4* vr1 = (const float4*)&vw[(n + 1) * D];
    const float4* vr2 = (const float4*)&vw[(n + 2) * D];
    const float4* vr3 = (const float4*)&vw[(n + 3) * D];
#pragma unroll
    for (int dq = 0; dq < 4; ++dq) {
      float4 v0 = vr0[dq], v1 = vr1[dq], v2 = vr2[dq], v3 = vr3[dq];
      oA[4 * dq + 0] = oA[4 * dq + 0] * scA + pA0 * v0.x + pA1 * v1.x + pA2 * v2.x + pA3 * v3.x;
      oA[4 * dq + 1] = oA[4 * dq + 1] * scA + pA0 * v0.y + pA1 * v1.y + pA2 * v2.y + pA3 * v3.y;
      oA[4 * dq + 2] = oA[4 * dq + 2] * scA + pA0 * v0.z + pA1 * v1.z + pA2 * v2.z + pA3 * v3.z;
      oA[4 * dq + 3] = oA[4 * dq + 3] * scA + pA0 * v0.w + pA1 * v1.w + pA2 * v2.w + pA3 * v3.w;
      oB[4 * dq + 0] = oB[4 * dq + 0] * scB + pB0 * v0.x + pB1 * v1.x + pB2 * v2.x + pB3 * v3.x;
      oB[4 * dq + 1] = oB[4 * dq + 1] * scB + pB0 * v0.y + pB1 * v1.y + pB2 * v2.y + pB3 * v3.y;
      oB[4 * dq + 2] = oB[4 * dq + 2] * scB + pB0 * v0.z + pB1 * v1.z + pB2 * v2.z + pB3 * v3.z;
      oB[4 * dq + 3] = oB[4 * dq + 3] * scB + pB0 * v0.w + pB1 * v1.w + pB2 * v2.w + pB3 * v3.w;
    }
    mA = mnA; mB = mnB;
    mk0 = nx0; mk1 = nx1;
  }
  {
    const float4* kr = (const float4*)&kw[100 * D];
    float4 k0 = kr[0], k1 = kr[1], k2 = kr[2], k3 = kr[3];
    float sA = dot16(qa0, qa1, qa2, qa3, k0, k1, k2, k3) * 0.25f + tm0;
    float sB = dot16(qb0, qb1, qb2, qb3, k0, k1, k2, k3) * 0.25f + tm1;
    float mnA = fmaxf(mA, sA), mnB = fmaxf(mB, sB);
    float scA = __expf(mA - mnA), scB = __expf(mB - mnB);
    float pA = __expf(sA - mnA), pB = __expf(sB - mnB);
    lA = lA * scA + pA;
    lB = lB * scB + pB;
    const float4* vr = (const float4*)&vw[100 * D];
#pragma unroll
    for (int dq = 0; dq < 4; ++dq) {
      float4 v0 = vr[dq];
      oA[4 * dq + 0] = oA[4 * dq + 0] * scA + pA * v0.x;
      oA[4 * dq + 1] = oA[4 * dq + 1] * scA + pA * v0.y;
      oA[4 * dq + 2] = oA[4 * dq + 2] * scA + pA * v0.z;
      oA[4 * dq + 3] = oA[4 * dq + 3] * scA + pA * v0.w;
      oB[4 * dq + 0] = oB[4 * dq + 0] * scB + pB * v0.x;
      oB[4 * dq + 1] = oB[4 * dq + 1] * scB + pB * v0.y;
      oB[4 * dq + 2] = oB[4 * dq + 2] * scB + pB * v0.z;
      oB[4 * dq + 3] = oB[4 * dq + 3] * scB + pB * v0.w;
    }
  }
  const float invA = 1.f / lA;
  float* xr0 = &x[((size_t)b * P + p0) * HD + h * D];
#pragma unroll
  for (int dq = 0; dq < 4; ++dq) {
    float4 t;
    t.x = oA[4 * dq + 0] * invA; t.y = oA[4 * dq + 1] * invA;
    t.z = oA[4 * dq + 2] * invA; t.w = oA[4 * dq + 3] * invA;
    *(float4*)&xr0[4 * dq] = t;
  }
  if (r1) {
    const float invB = 1.f / lB;
    float* xr1 = &x[((size_t)b * P + p1) * HD + h * D];
#pragma unroll
    for (int dq = 0; dq < 4; ++dq) {
      float4 t;
      t.x = oB[4 * dq + 0] * invB; t.y = oB[4 * dq + 1] * invB;
      t.z = oB[4 * dq + 2] * invB; t.w = oB[4 * dq + 3] * invB;
      *(float4*)&xr1[4 * dq] = t;
    }
  }
}

// ---------------------------------------------------------------------------
// Kernel 4: router logits (fp32) + top2 + gates; ALSO emits xsplit (hi/lo
// bf16 planes of x) for the MFMA expert GEMM.  Routing math unchanged.
// xsplit layout: [tok][plane(2)][256] ushort  (1 KB per token)
// ---------------------------------------------------------------------------
__global__ __launch_bounds__(256) void logits_top2_kernel(
    const float* __restrict__ x, const float* __restrict__ Wg,
    int* __restrict__ topi, float* __restrict__ topg,
    ushort_t* __restrict__ xsplit) {
  __shared__ float xl[32][260];
  __shared__ float wg[E * NE];
  __shared__ float lg[32][9];
  const int tid = threadIdx.x;
  const int t0 = blockIdx.x * 32;
  for (int r = 0; r < 32; ++r) {
    float val = x[(size_t)(t0 + r) * HD + tid];
    xl[r][tid] = val;
    unsigned short hi = f2bf(val);
    unsigned short lo = f2bf(val - bf2f(hi));
    xsplit[(size_t)(t0 + r) * 512 + tid] = hi;
    xsplit[(size_t)(t0 + r) * 512 + 256 + tid] = lo;
  }
  for (int i = tid; i < E * NE; i += 256) wg[i] = Wg[i];
  __syncthreads();
  const int r = tid >> 3, e = tid & 7;
  float acc = 0.f;
  for (int f = 0; f < E; ++f) acc += xl[r][f] * wg[f * NE + e];
  lg[r][e] = acc;
  __syncthreads();
  if (tid < 32) {
    float v[8];
#pragma unroll
    for (int j = 0; j < 8; ++j) v[j] = lg[tid][j];
    int i1 = 0; float v1 = v[0];
#pragma unroll
    for (int j = 1; j < 8; ++j) if (v[j] > v1) { v1 = v[j]; i1 = j; }
    int i2 = -1; float v2 = -1e30f;
#pragma unroll
    for (int j = 0; j < 8; ++j)
      if (j != i1 && v[j] > v2) { v2 = v[j]; i2 = j; }
    float ex = __expf(v2 - v1);
    float g1 = 1.f / (1.f + ex);
    float g2 = ex / (1.f + ex);
    int t = t0 + tid;
    topi[t * 2 + 0] = i1; topi[t * 2 + 1] = i2;
    topg[t * 2 + 0] = g1; topg[t * 2 + 1] = g2;
  }
}

// ---------------------------------------------------------------------------
// Kernel 5: build per-expert token lists. UNCHANGED.
// ---------------------------------------------------------------------------
__global__ __launch_bounds__(1024) void build_lists_kernel(
    const int* __restrict__ topi, const float* __restrict__ topg,
    int* __restrict__ list_tok, float* __restrict__ list_gate,
    int* __restrict__ counts) {
  const int e = blockIdx.x;
  const int tid = threadIdx.x;
  const int lane = tid & 63, w = tid >> 6;
  __shared__ int wsum[16];
  int running = 0;
  for (int c = 0; c < NTOK; c += 1024) {
    int t = c + tid;
    int ia = topi[t * 2 + 0], ib = topi[t * 2 + 1];
    int slot = (ia == e) ? 0 : ((ib == e) ? 1 : -1);
    int f = (slot >= 0) ? 1 : 0;
    unsigned long long m = __ballot(f);
    if (lane == 0) wsum[w] = __popcll(m);
    __syncthreads();
    int wbase = 0, total = 0;
#pragma unroll
    for (int i = 0; i < 16; ++i) {
      int s = wsum[i];
      if (i < w) wbase += s;
      total += s;
    }
    if (f) {
      int prefix = __popcll(m & ((1ull << lane) - 1ull));
      int pos = running + wbase + prefix;
      list_tok[e * NTOK + pos] = (t << 1) | slot;
      list_gate[e * NTOK + pos] = topg[t * 2 + slot];
    }
    running += total;
    __syncthreads();
  }
  if (tid == 0) counts[e] = running;
}

// ---------------------------------------------------------------------------
// Kernel 5b: pre-pack expert weights into per-lane MFMA fragment order,
// split into bf16 hi/lo planes.  Wp layout (uint4 units):
//   idx = (((e*8+kt)*16+gct)*2+plane)*64 + lane   -> 8 ushorts (k-consecutive)
// where for B-fragment: k = kt*32 + (lane>>4)*8 + j,  col = gct*16 + (lane&15)
// ---------------------------------------------------------------------------
__global__ __launch_bounds__(256) void wsplit_kernel(
    const float* __restrict__ eW, uint4* __restrict__ Wp) {
  const int gid = blockIdx.x * 256 + threadIdx.x;   // 0 .. 65535
  const int lane = gid & 63;
  const int rest = gid >> 6;        // e*128 + kt*16 + gct
  const int gct = rest & 15;
  const int kt = (rest >> 4) & 7;
  const int e = rest >> 7;
  const int kbase = kt * 32 + (lane >> 4) * 8;
  const int c = gct * 16 + (lane & 15);
  unsigned int hi[4], lo[4];
#pragma unroll
  for (int jj = 0; jj < 4; ++jj) {
    float v0 = eW[((size_t)e * HD + (kbase + 2 * jj)) * E + c];
    float v1 = eW[((size_t)e * HD + (kbase + 2 * jj + 1)) * E + c];
    unsigned short h0 = f2bf(v0), h1 = f2bf(v1);
    unsigned short l0 = f2bf(v0 - bf2f(h0)), l1 = f2bf(v1 - bf2f(h1));
    hi[jj] = (unsigned int)h0 | ((unsigned int)h1 << 16);
    lo[jj] = (unsigned int)l0 | ((unsigned int)l1 << 16);
  }
  uint4 uh, ul;
  uh.x = hi[0]; uh.y = hi[1]; uh.z = hi[2]; uh.w = hi[3];
  ul.x = lo[0]; ul.y = lo[1]; ul.z = lo[2]; ul.w = lo[3];
  Wp[(size_t)(rest * 2 + 0) * 64 + lane] = uh;
  Wp[(size_t)(rest * 2 + 1) * 64 + lane] = ul;
}

// ---------------------------------------------------------------------------
// Kernel 6: sparse expert GEMM via split-bf16 MFMA (hi*hi + hi*lo + lo*hi).
// Block 256 = 4 waves; tile 32 tokens x 256 cols; wave = 32 tok x 64 cols.
// A from LDS (token rows, 16B-padded), B from pre-packed Wp (coalesced).
// ---------------------------------------------------------------------------
__global__ __launch_bounds__(256) void expert_gemm_kernel(
    const ushort_t* __restrict__ xsplit, const uint4* __restrict__ Wp,
    const float* __restrict__ eb, const int* __restrict__ list_tok,
    const float* __restrict__ list_gate, const int* __restrict__ counts,
    float* __restrict__ p0, float* __restrict__ p1) {
  int e = 0, t0 = -1;
  {
    int rem = blockIdx.x;
    for (int i = 0; i < NE; ++i) {
      int nt = (counts[i] + 31) >> 5;
      if (rem < nt) { e = i; t0 = rem * 32; break; }
      rem -= nt;
    }
  }
  if (t0 < 0) return;
  const int cnt = counts[e];
  const int nr = min(32, cnt - t0);
  __shared__ uint4 xls[32 * 65];   // 32 rows x (2 planes x 32 + 1 pad) uint4
  __shared__ int stok[32];
  __shared__ float sg[32];
  const int tid = threadIdx.x;
  if (tid < 32) {
    int src = e * NTOK + t0 + ((tid < nr) ? tid : 0);
    stok[tid] = list_tok[src];
    sg[tid] = (tid < nr) ? list_gate[e * NTOK + t0 + tid] : 0.f;
  }
  __syncthreads();
  for (int i = tid; i < 32 * 64; i += 256) {
    int r = i >> 6, ch = i & 63;
    const uint4* src = (const uint4*)(xsplit + (size_t)(stok[r] >> 1) * 512);
    xls[r * 65 + ch] = src[ch];
  }
  __syncthreads();
  const int w = tid >> 6;
  const int lane = tid & 63;
  const int lr = lane & 15;       // token-row within 16 / col within 16
  const int lg4 = lane >> 4;      // k-group
  f32x4 acc[2][4];
#pragma unroll
  for (int rt = 0; rt < 2; ++rt)
#pragma unroll
    for (int ct = 0; ct < 4; ++ct) acc[rt][ct] = (f32x4){0.f, 0.f, 0.f, 0.f};

  for (int kt = 0; kt < 8; ++kt) {
    short8 afrag[2][2];
#pragma unroll
    for (int rt = 0; rt < 2; ++rt)
#pragma unroll
      for (int pl = 0; pl < 2; ++pl) {
        uint4 u = xls[(rt * 16 + lr) * 65 + pl * 32 + kt * 4 + lg4];
        afrag[rt][pl] = __builtin_bit_cast(short8, u);
      }
#pragma unroll
    for (int ct = 0; ct < 4; ++ct) {
      const int gct = w * 4 + ct;
      const size_t base = (size_t)(((e * 8 + kt) * 16 + gct) * 2) * 64 + lane;
      short8 bh = __builtin_bit_cast(short8, Wp[base]);
      short8 bl = __builtin_bit_cast(short8, Wp[base + 64]);
#pragma unroll
      for (int rt = 0; rt < 2; ++rt) {
        acc[rt][ct] = __builtin_amdgcn_mfma_f32_16x16x32_bf16(
            afrag[rt][0], bh, acc[rt][ct], 0, 0, 0);
        acc[rt][ct] = __builtin_amdgcn_mfma_f32_16x16x32_bf16(
            afrag[rt][0], bl, acc[rt][ct], 0, 0, 0);
        acc[rt][ct] = __builtin_amdgcn_mfma_f32_16x16x32_bf16(
            afrag[rt][1], bh, acc[rt][ct], 0, 0, 0);
      }
    }
  }
  // epilogue: D[row][col], row = (lane>>4)*4 + reg, col = lane&15
#pragma unroll
  for (int rt = 0; rt < 2; ++rt) {
#pragma unroll
    for (int ct = 0; ct < 4; ++ct) {
      const int col = (w * 4 + ct) * 16 + lr;
      const float bias = eb[e * E + col];
#pragma unroll
      for (int reg = 0; reg < 4; ++reg) {
        const int ridx = rt * 16 + lg4 * 4 + reg;
        if (ridx < nr) {
          const int tokw = stok[ridx];
          const float g = sg[ridx];
          float* dst = ((tokw & 1) ? p1 : p0) + (size_t)(tokw >> 1) * E + col;
          *dst = g * (acc[rt][ct][reg] + bias);
        }
      }
    }
  }
}

// ---------------------------------------------------------------------------
// Kernel 7: score2 = mh @ enc^T, per batch. grid (4, 256), block 128.
// ---------------------------------------------------------------------------
__global__ __launch_bounds__(128) void score2_kernel(
    const float* __restrict__ p0, const float* __restrict__ p1,
    const float* __restrict__ enc, float* __restrict__ out) {
  const int b = blockIdx.y;
  const int pt = blockIdx.x * 25;
  __shared__ float mh[25][E];
  const int tid = threadIdx.x;
  for (int i = tid; i < 25 * E; i += 128) {
    int r = i >> 8, c = i & 255;
    int t = b * P + pt + r;
    mh[r][c] = p0[(size_t)t * E + c] + p1[(size_t)t * E + c];
  }
  __syncthreads();
  const int n = tid;
  if (n >= N1) return;
  float acc[25];
#pragma unroll
  for (int r = 0; r < 25; ++r) acc[r] = 0.f;
  const float* er = enc + ((size_t)b * N1 + n) * E;
  for (int ee = 0; ee < E; ee += 4) {
    float4 ev = *(const float4*)&er[ee];
#pragma unroll
    for (int r = 0; r < 25; ++r) {
      float4 mv = *(const float4*)&mh[r][ee];
      acc[r] += mv.x * ev.x + mv.y * ev.y + mv.z * ev.z + mv.w * ev.w;
    }
  }
#pragma unroll
  for (int r = 0; r < 25; ++r) out[((size_t)b * P + pt + r) * N1 + n] = acc[r];
}

// ---------------------------------------------------------------------------
// Kernel 8: add biases, tanh clip, + ninf, row softmax.  In-place on d_out.
// ---------------------------------------------------------------------------
__global__ __launch_bounds__(256) void softmax2_kernel(
    float* __restrict__ sc, const float* __restrict__ ab,
    const float* __restrict__ ab1, const float* __restrict__ ninf) {
  const int row = blockIdx.x * 4 + (threadIdx.x >> 6);
  const int lane = threadIdx.x & 63;
  float* srow = sc + (size_t)row * N1;
  const float* a = ab + (size_t)row * N1;
  const float* a1 = ab1 + (size_t)row * N1;
  const float* nf = ninf + (size_t)row * N1;
  float s0 = -1e30f, s1 = -1e30f;
  {
    int i = lane;
    float s = srow[i] + a[i] + a1[i];
    float e2 = __expf(s * 0.125f);
    float th = 1.f - 2.f / (e2 + 1.f);
    s0 = 10.f * th + nf[i];
  }
  if (lane < N1 - 64) {
    int i = lane + 64;
    float s = srow[i] + a[i] + a1[i];
    float e2 = __expf(s * 0.125f);
    float th = 1.f - 2.f / (e2 + 1.f);
    s1 = 10.f * th + nf[i];
  }
  float mx = fmaxf(s0, s1);
#pragma unroll
  for (int off = 32; off > 0; off >>= 1) mx = fmaxf(mx, __shfl_xor(mx, off, 64));
  float p0 = __expf(s0 - mx);
  float p1 = (lane < N1 - 64) ? __expf(s1 - mx) : 0.f;
  float sum = p0 + p1;
#pragma unroll
  for (int off = 32; off > 0; off >>= 1) sum += __shfl_xor(sum, off, 64);
  float inv = 1.f / sum;
  srow[lane] = p0 * inv;
  if (lane < N1 - 64) srow[lane + 64] = p1 * inv;
}

// ---------------------------------------------------------------------------
extern "C" void kernel_launch(void* const* d_in, const int* in_sizes, int n_in,
                              void* d_out, int out_size, void* d_ws,
                              size_t ws_size, hipStream_t stream) {
  const float* eln  = (const float*)d_in[0];
  const float* attr = (const float*)d_in[1];
  const float* enc  = (const float*)d_in[2];
  const float* ninf = (const float*)d_in[3];
  const float* ab   = (const float*)d_in[4];
  const float* ab1  = (const float*)d_in[5];
  const float* Wq   = (const float*)d_in[6];
  const float* Wk   = (const float*)d_in[7];
  const float* Wv   = (const float*)d_in[8];
  const float* Wg   = (const float*)d_in[9];
  const float* eW   = (const float*)d_in[10];
  const float* eb   = (const float*)d_in[11];
  float* out = (float*)d_out;

  char* ws = (char*)d_ws;
  size_t off = 0;
  auto carve = [&](size_t bytes) {
    char* p = ws + off;
    off += (bytes + 255) & ~size_t(255);
    return p;
  };
  float* kbuf = (float*)carve(sizeof(float) * NKV * HD);
  float* vbuf = (float*)carve(sizeof(float) * NKV * HD);
  float* qbuf = (float*)carve(sizeof(float) * NTOK * HD);
  float* xbuf = (float*)carve(sizeof(float) * NTOK * HD);
  int*   topi = (int*)carve(sizeof(int) * NTOK * 2);
  float* topg = (float*)carve(sizeof(float) * NTOK * 2);
  int*   counts = (int*)carve(sizeof(int) * 16);
  int*   list_tok = (int*)carve(sizeof(int) * NE * NTOK);
  float* list_gate = (float*)carve(sizeof(float) * NE * NTOK);
  uint4* Wp = (uint4*)carve(sizeof(ushort_t) * NE * HD * E * 2);  // 2 MB
  // aliases: p0/p1 on k/v bufs (dead after attn); xsplit on qbuf (dead after attn)
  float* pp0 = kbuf;
  float* pp1 = vbuf;
  ushort_t* xsplit = (ushort_t*)qbuf;

  wsplit_kernel<<<256, 256, 0, stream>>>(eW, Wp);
  dim3 kvg(NKV / 32, 2);
  kv_proj_kernel<<<kvg, 256, 0, stream>>>(enc, Wk, Wv, kbuf, vbuf);
  q_proj_kernel<<<NTOK / 32, 256, 0, stream>>>(eln, attr, Wq, qbuf);
  attn_kernel<<<B * 4, 256, 0, stream>>>(qbuf, kbuf, vbuf, ninf, xbuf);
  logits_top2_kernel<<<NTOK / 32, 256, 0, stream>>>(xbuf, Wg, topi, topg,
                                                    xsplit);
  build_lists_kernel<<<NE, 1024, 0, stream>>>(topi, topg, list_tok, list_gate,
                                              counts);
  // max tiles = 2*NTOK/32 + NE = 1600 + 8
  expert_gemm_kernel<<<1608, 256, 0, stream>>>(xsplit, Wp, eb, list_tok,
                                               list_gate, counts, pp0, pp1);
  dim3 s2(4, B);
  score2_kernel<<<s2, 128, 0, stream>>>(pp0, pp1, enc, out);
  softmax2_kernel<<<NTOK / 4, 256, 0, stream>>>(out, ab, ab1, ninf);
}

// Round 7
// 336.595 us; speedup vs baseline: 1.5051x; 1.1999x over previous
//
#include <hip/hip_runtime.h>
#include <hip/hip_bf16.h>

// Problem constants
#define B   256
#define P   100
#define N1  101
#define E   256
#define HD  256          // H*D
#define H   16
#define D   16
#define NE  8
#define NTOK (B*P)       // 25600
#define NKV  (B*N1)      // 25856

typedef __attribute__((ext_vector_type(8))) short short8;
typedef __attribute__((ext_vector_type(4))) float f32x4;
typedef unsigned short ushort_t;

__device__ __forceinline__ unsigned short f2bf(float f) {
  unsigned int u = __float_as_uint(f);
  unsigned int r = (u + 0x7fffu + ((u >> 16) & 1u)) >> 16;
  return (unsigned short)r;
}
__device__ __forceinline__ float bf2f(unsigned short b) {
  return __uint_as_float(((unsigned int)b) << 16);
}

// ---------------------------------------------------------------------------
// wsplit3: pre-pack a K x 256 fp32 weight into 3-plane (hi/mid/lo) bf16
// fragment order. Layout (uint4): [((kt*16+gct)*3+p)*64 + lane],
// k = kt*32 + (lane>>4)*8 + j, col = gct*16 + (lane&15). Zeros for k>=Kreal.
// ---------------------------------------------------------------------------
__global__ __launch_bounds__(256) void wsplit3_kernel(
    const float* __restrict__ W, uint4* __restrict__ Wp, int Kreal) {
  const int gid = blockIdx.x * 256 + threadIdx.x;
  const int lane = gid & 63;
  const int rest = gid >> 6;          // kt*16 + gct
  const int gct = rest & 15;
  const int kt = rest >> 4;
  const int k0 = kt * 32 + (lane >> 4) * 8;
  const int c = gct * 16 + (lane & 15);
  unsigned int hw[4], mw[4], lw[4];
#pragma unroll
  for (int jj = 0; jj < 4; ++jj) {
    int ka = k0 + 2 * jj, kb = ka + 1;
    float va = (ka < Kreal) ? W[(size_t)ka * 256 + c] : 0.f;
    float vb = (kb < Kreal) ? W[(size_t)kb * 256 + c] : 0.f;
    unsigned short ha = f2bf(va), hb = f2bf(vb);
    float ra = va - bf2f(ha), rb = vb - bf2f(hb);
    unsigned short ma = f2bf(ra), mb = f2bf(rb);
    unsigned short la = f2bf(ra - bf2f(ma)), lb = f2bf(rb - bf2f(mb));
    hw[jj] = (unsigned int)ha | ((unsigned int)hb << 16);
    mw[jj] = (unsigned int)ma | ((unsigned int)mb << 16);
    lw[jj] = (unsigned int)la | ((unsigned int)lb << 16);
  }
  uint4 uh, um, ul;
  uh.x = hw[0]; uh.y = hw[1]; uh.z = hw[2]; uh.w = hw[3];
  um.x = mw[0]; um.y = mw[1]; um.z = mw[2]; um.w = mw[3];
  ul.x = lw[0]; ul.y = lw[1]; ul.z = lw[2]; ul.w = lw[3];
  Wp[(size_t)(rest * 3 + 0) * 64 + lane] = uh;
  Wp[(size_t)(rest * 3 + 1) * 64 + lane] = um;
  Wp[(size_t)(rest * 3 + 2) * 64 + lane] = ul;
}

// ---------------------------------------------------------------------------
// proj3: 3-plane split-bf16 MFMA GEMM, tile 32 rows x 256 cols, 4 waves.
// A: split on the fly into LDS fragment layout; B: prepacked Wp3.
// 6 products: hh + hm + mh + mm + hl + lh  (residual ~2^-27 relative).
// MODE 0: kv (rows->B,H,N1,D), MODE 1: q (rows->B,H,P,D, K=260 in 9 ktiles).
// ---------------------------------------------------------------------------
template <int KT, int MODE>
__global__ __launch_bounds__(256) void proj3_kernel(
    const float* __restrict__ src, const float* __restrict__ attr,
    const uint4* __restrict__ Wp3, float* __restrict__ outp) {
  const int RSTRIDE = KT * 12 + 1;     // per-row uint4 stride (3 planes * KT*4, +1 pad)
  __shared__ uint4 als[32 * (KT * 12 + 1)];
  const int tid = threadIdx.x;
  const int row0 = blockIdx.x * 32;
  // ---- stage A: read fp32 rows, split 3-plane, write fragment slots ----
  const int NKG = KT * 4;              // k-groups of 8
  for (int i = tid; i < 32 * NKG; i += 256) {
    const int row = i / NKG;
    const int kg = i - row * NKG;
    float v[8];
    if (MODE == 0) {
      const float4* s = (const float4*)(src + (size_t)(row0 + row) * 256 + kg * 8);
      float4 x0 = s[0], x1 = s[1];
      v[0] = x0.x; v[1] = x0.y; v[2] = x0.z; v[3] = x0.w;
      v[4] = x1.x; v[5] = x1.y; v[6] = x1.z; v[7] = x1.w;
    } else {
      const int kbase = kg * 8;
      if (kbase < 256) {
        const float4* s = (const float4*)(src + (size_t)(row0 + row) * 256 + kbase);
        float4 x0 = s[0], x1 = s[1];
        v[0] = x0.x; v[1] = x0.y; v[2] = x0.z; v[3] = x0.w;
        v[4] = x1.x; v[5] = x1.y; v[6] = x1.z; v[7] = x1.w;
      } else {
#pragma unroll
        for (int j = 0; j < 8; ++j) {
          int k = kbase + j;
          v[j] = (k >= 256 && k < 260) ? attr[(size_t)(row0 + row) * 4 + (k - 256)]
                                       : 0.f;
        }
      }
    }
    unsigned int hw[4], mw[4], lw[4];
#pragma unroll
    for (int jj = 0; jj < 4; ++jj) {
      float va = v[2 * jj], vb = v[2 * jj + 1];
      unsigned short ha = f2bf(va), hb = f2bf(vb);
      float ra = va - bf2f(ha), rb = vb - bf2f(hb);
      unsigned short ma = f2bf(ra), mb = f2bf(rb);
      unsigned short la = f2bf(ra - bf2f(ma)), lb = f2bf(rb - bf2f(mb));
      hw[jj] = (unsigned int)ha | ((unsigned int)hb << 16);
      mw[jj] = (unsigned int)ma | ((unsigned int)mb << 16);
      lw[jj] = (unsigned int)la | ((unsigned int)lb << 16);
    }
    uint4 uh, um, ul;
    uh.x = hw[0]; uh.y = hw[1]; uh.z = hw[2]; uh.w = hw[3];
    um.x = mw[0]; um.y = mw[1]; um.z = mw[2]; um.w = mw[3];
    ul.x = lw[0]; ul.y = lw[1]; ul.z = lw[2]; ul.w = lw[3];
    const int slot = row * RSTRIDE + kg;     // kg == kt*4 + lg4
    als[slot] = uh;
    als[slot + NKG] = um;
    als[slot + 2 * NKG] = ul;
  }
  __syncthreads();
  // ---- MFMA main loop ----
  const int w = tid >> 6;
  const int lane = tid & 63;
  const int lr = lane & 15;
  const int lg4 = lane >> 4;
  f32x4 acc[2][4];
#pragma unroll
  for (int rt = 0; rt < 2; ++rt)
#pragma unroll
    for (int ct = 0; ct < 4; ++ct) acc[rt][ct] = (f32x4){0.f, 0.f, 0.f, 0.f};
  for (int kt = 0; kt < KT; ++kt) {
    short8 ah[2], am[2], al[2];
#pragma unroll
    for (int rt = 0; rt < 2; ++rt) {
      const int base = (rt * 16 + lr) * RSTRIDE + kt * 4 + lg4;
      ah[rt] = __builtin_bit_cast(short8, als[base]);
      am[rt] = __builtin_bit_cast(short8, als[base + NKG]);
      al[rt] = __builtin_bit_cast(short8, als[base + 2 * NKG]);
    }
#pragma unroll
    for (int ct = 0; ct < 4; ++ct) {
      const int gct = w * 4 + ct;
      const size_t base = (size_t)((kt * 16 + gct) * 3) * 64 + lane;
      short8 bh = __builtin_bit_cast(short8, Wp3[base]);
      short8 bm = __builtin_bit_cast(short8, Wp3[base + 64]);
      short8 bl = __builtin_bit_cast(short8, Wp3[base + 128]);
#pragma unroll
      for (int rt = 0; rt < 2; ++rt) {
        f32x4 a = acc[rt][ct];
        a = __builtin_amdgcn_mfma_f32_16x16x32_bf16(ah[rt], bh, a, 0, 0, 0);
        a = __builtin_amdgcn_mfma_f32_16x16x32_bf16(ah[rt], bm, a, 0, 0, 0);
        a = __builtin_amdgcn_mfma_f32_16x16x32_bf16(am[rt], bh, a, 0, 0, 0);
        a = __builtin_amdgcn_mfma_f32_16x16x32_bf16(am[rt], bm, a, 0, 0, 0);
        a = __builtin_amdgcn_mfma_f32_16x16x32_bf16(ah[rt], bl, a, 0, 0, 0);
        a = __builtin_amdgcn_mfma_f32_16x16x32_bf16(al[rt], bh, a, 0, 0, 0);
        acc[rt][ct] = a;
      }
    }
  }
  // ---- epilogue: D row = lg4*4+reg (+rt*16), col = gct*16 + lr ----
#pragma unroll
  for (int rt = 0; rt < 2; ++rt) {
#pragma unroll
    for (int ct = 0; ct < 4; ++ct) {
      const int gct = w * 4 + ct;         // head index
#pragma unroll
      for (int reg = 0; reg < 4; ++reg) {
        const int row = row0 + rt * 16 + lg4 * 4 + reg;
        size_t o;
        if (MODE == 0) {
          int bb = row / N1, nn = row - bb * N1;
          o = (((size_t)bb * H + gct) * N1 + nn) * D + lr;
        } else {
          int bb = row / P, pp = row - bb * P;
          o = (((size_t)bb * H + gct) * P + pp) * D + lr;
        }
        outp[o] = acc[rt][ct][reg];
      }
    }
  }
}

// ---------------------------------------------------------------------------
// Kernel 3: attention. Block = 256 threads = 4 waves = 4 heads of one batch.
// ---------------------------------------------------------------------------
__device__ __forceinline__ float dot16(
    const float4& a0, const float4& a1, const float4& a2, const float4& a3,
    const float4& b0, const float4& b1, const float4& b2, const float4& b3) {
  return a0.x * b0.x + a0.y * b0.y + a0.z * b0.z + a0.w * b0.w +
         a1.x * b1.x + a1.y * b1.y + a1.z * b1.z + a1.w * b1.w +
         a2.x * b2.x + a2.y * b2.y + a2.z * b2.z + a2.w * b2.w +
         a3.x * b3.x + a3.y * b3.y + a3.z * b3.z + a3.w * b3.w;
}

__global__ __launch_bounds__(256) void attn_kernel(
    const float* __restrict__ q, const float* __restrict__ k,
    const float* __restrict__ v, const float* __restrict__ ninf,
    float* __restrict__ x) {
  const int b = blockIdx.x >> 2;
  const int h0 = (blockIdx.x & 3) * 4;
  __shared__ float kl[4 * N1 * D];
  __shared__ float vl[4 * N1 * D];
  const int tid = threadIdx.x;
  {
    const float4* ks = (const float4*)(k + ((size_t)b * H + h0) * N1 * D);
    const float4* vs = (const float4*)(v + ((size_t)b * H + h0) * N1 * D);
    float4* kd = (float4*)kl;
    float4* vd = (float4*)vl;
    for (int i = tid; i < N1 * D; i += 256) { kd[i] = ks[i]; vd[i] = vs[i]; }
  }
  const int w = tid >> 6;
  const int lane = tid & 63;
  const int h = h0 + w;
  const int p0 = lane;
  const bool r1 = (lane + 64 < P);
  const int p1 = r1 ? (lane + 64) : (P - 1);
  const float* qb = q + (((size_t)b * H + h) * P) * D;
  float4 qa0 = *(const float4*)&qb[p0 * D + 0];
  float4 qa1 = *(const float4*)&qb[p0 * D + 4];
  float4 qa2 = *(const float4*)&qb[p0 * D + 8];
  float4 qa3 = *(const float4*)&qb[p0 * D + 12];
  float4 qb0 = *(const float4*)&qb[p1 * D + 0];
  float4 qb1 = *(const float4*)&qb[p1 * D + 4];
  float4 qb2 = *(const float4*)&qb[p1 * D + 8];
  float4 qb3 = *(const float4*)&qb[p1 * D + 12];
  const float* m0 = ninf + ((size_t)b * P + p0) * N1;
  const float* m1 = ninf + ((size_t)b * P + p1) * N1;
  const float* kw = kl + w * N1 * D;
  const float* vw = vl + w * N1 * D;
  __syncthreads();

  float mA = -1e30f, mB = -1e30f, lA = 0.f, lB = 0.f;
  float oA[16], oB[16];
#pragma unroll
  for (int d = 0; d < 16; ++d) { oA[d] = 0.f; oB[d] = 0.f; }
  float4 mk0 = *(const float4*)&m0[0];
  float4 mk1 = *(const float4*)&m1[0];
  const float tm0 = m0[100], tm1 = m1[100];

  for (int it = 0; it < 25; ++it) {
    const int n = it * 4;
    const int nn = (it < 24) ? (n + 4) : 0;
    float4 nx0 = *(const float4*)&m0[nn];
    float4 nx1 = *(const float4*)&m1[nn];
    const float4* kr0 = (const float4*)&kw[(n + 0) * D];
    const float4* kr1 = (const float4*)&kw[(n + 1) * D];
    const float4* kr2 = (const float4*)&kw[(n + 2) * D];
    const float4* kr3 = (const float4*)&kw[(n + 3) * D];
    float4 k00 = kr0[0], k01 = kr0[1], k02 = kr0[2], k03 = kr0[3];
    float4 k10 = kr1[0], k11 = kr1[1], k12 = kr1[2], k13 = kr1[3];
    float4 k20 = kr2[0], k21 = kr2[1], k22 = kr2[2], k23 = kr2[3];
    float4 k30 = kr3[0], k31 = kr3[1], k32 = kr3[2], k33 = kr3[3];
    float sA0 = dot16(qa0, qa1, qa2, qa3, k00, k01, k02, k03) * 0.25f + mk0.x;
    float sA1 = dot16(qa0, qa1, qa2, qa3, k10, k11, k12, k13) * 0.25f + mk0.y;
    float sA2 = dot16(qa0, qa1, qa2, qa3, k20, k21, k22, k23) * 0.25f + mk0.z;
    float sA3 = dot16(qa0, qa1, qa2, qa3, k30, k31, k32, k33) * 0.25f + mk0.w;
    float sB0 = dot16(qb0, qb1, qb2, qb3, k00, k01, k02, k03) * 0.25f + mk1.x;
    float sB1 = dot16(qb0, qb1, qb2, qb3, k10, k11, k12, k13) * 0.25f + mk1.y;
    float sB2 = dot16(qb0, qb1, qb2, qb3, k20, k21, k22, k23) * 0.25f + mk1.z;
    float sB3 = dot16(qb0, qb1, qb2, qb3, k30, k31, k32, k33) * 0.25f + mk1.w;
    float mnA = fmaxf(fmaxf(fmaxf(sA0, sA1), fmaxf(sA2, sA3)), mA);
    float mnB = fmaxf(fmaxf(fmaxf(sB0, sB1), fmaxf(sB2, sB3)), mB);
    float scA = __expf(mA - mnA);
    float scB = __expf(mB - mnB);
    float pA0 = __expf(sA0 - mnA), pA1 = __expf(sA1 - mnA);
    float pA2 = __expf(sA2 - mnA), pA3 = __expf(sA3 - mnA);
    float pB0 = __expf(sB0 - mnB), pB1 = __expf(sB1 - mnB);
    float pB2 = __expf(sB2 - mnB), pB3 = __expf(sB3 - mnB);
    lA = lA * scA + (pA0 + pA1) + (pA2 + pA3);
    lB = lB * scB + (pB0 + pB1) + (pB2 + pB3);
    const float4* vr0 = (const float4*)&vw[(n + 0) * D];
    const float4* vr1 = (const float4*)&vw[(n + 1) * D];
    const float4* vr2 = (const float4*)&vw[(n + 2) * D];
    const float4* vr3 = (const float4*)&vw[(n + 3) * D];
#pragma unroll
    for (int dq = 0; dq < 4; ++dq) {
      float4 v0 = vr0[dq], v1 = vr1[dq], v2 = vr2[dq], v3 = vr3[dq];
      oA[4 * dq + 0] = oA[4 * dq + 0] * scA + pA0 * v0.x + pA1 * v1.x + pA2 * v2.x + pA3 * v3.x;
      oA[4 * dq + 1] = oA[4 * dq + 1] * scA + pA0 * v0.y + pA1 * v1.y + pA2 * v2.y + pA3 * v3.y;
      oA[4 * dq + 2] = oA[4 * dq + 2] * scA + pA0 * v0.z + pA1 * v1.z + pA2 * v2.z + pA3 * v3.z;
      oA[4 * dq + 3] = oA[4 * dq + 3] * scA + pA0 * v0.w + pA1 * v1.w + pA2 * v2.w + pA3 * v3.w;
      oB[4 * dq + 0] = oB[4 * dq + 0] * scB + pB0 * v0.x + pB1 * v1.x + pB2 * v2.x + pB3 * v3.x;
      oB[4 * dq + 1] = oB[4 * dq + 1] * scB + pB0 * v0.y + pB1 * v1.y + pB2 * v2.y + pB3 * v3.y;
      oB[4 * dq + 2] = oB[4 * dq + 2] * scB + pB0 * v0.z + pB1 * v1.z + pB2 * v2.z + pB3 * v3.z;
      oB[4 * dq + 3] = oB[4 * dq + 3] * scB + pB0 * v0.w + pB1 * v1.w + pB2 * v2.w + pB3 * v3.w;
    }
    mA = mnA; mB = mnB;
    mk0 = nx0; mk1 = nx1;
  }
  {
    const float4* kr = (const float4*)&kw[100 * D];
    float4 k0 = kr[0], k1 = kr[1], k2 = kr[2], k3 = kr[3];
    float sA = dot16(qa0, qa1, qa2, qa3, k0, k1, k2, k3) * 0.25f + tm0;
    float sB = dot16(qb0, qb1, qb2, qb3, k0, k1, k2, k3) * 0.25f + tm1;
    float mnA = fmaxf(mA, sA), mnB = fmaxf(mB, sB);
    float scA = __expf(mA - mnA), scB = __expf(mB - mnB);
    float pA = __expf(sA - mnA), pB = __expf(sB - mnB);
    lA = lA * scA + pA;
    lB = lB * scB + pB;
    const float4* vr = (const float4*)&vw[100 * D];
#pragma unroll
    for (int dq = 0; dq < 4; ++dq) {
      float4 v0 = vr[dq];
      oA[4 * dq + 0] = oA[4 * dq + 0] * scA + pA * v0.x;
      oA[4 * dq + 1] = oA[4 * dq + 1] * scA + pA * v0.y;
      oA[4 * dq + 2] = oA[4 * dq + 2] * scA + pA * v0.z;
      oA[4 * dq + 3] = oA[4 * dq + 3] * scA + pA * v0.w;
      oB[4 * dq + 0] = oB[4 * dq + 0] * scB + pB * v0.x;
      oB[4 * dq + 1] = oB[4 * dq + 1] * scB + pB * v0.y;
      oB[4 * dq + 2] = oB[4 * dq + 2] * scB + pB * v0.z;
      oB[4 * dq + 3] = oB[4 * dq + 3] * scB + pB * v0.w;
    }
  }
  const float invA = 1.f / lA;
  float* xr0 = &x[((size_t)b * P + p0) * HD + h * D];
#pragma unroll
  for (int dq = 0; dq < 4; ++dq) {
    float4 t;
    t.x = oA[4 * dq + 0] * invA; t.y = oA[4 * dq + 1] * invA;
    t.z = oA[4 * dq + 2] * invA; t.w = oA[4 * dq + 3] * invA;
    *(float4*)&xr0[4 * dq] = t;
  }
  if (r1) {
    const float invB = 1.f / lB;
    float* xr1 = &x[((size_t)b * P + p1) * HD + h * D];
#pragma unroll
    for (int dq = 0; dq < 4; ++dq) {
      float4 t;
      t.x = oB[4 * dq + 0] * invB; t.y = oB[4 * dq + 1] * invB;
      t.z = oB[4 * dq + 2] * invB; t.w = oB[4 * dq + 3] * invB;
      *(float4*)&xr1[4 * dq] = t;
    }
  }
}

// ---------------------------------------------------------------------------
// Kernel 4: router logits (fp32) + top2 + gates; emits xsplit (2-plane).
// ---------------------------------------------------------------------------
__global__ __launch_bounds__(256) void logits_top2_kernel(
    const float* __restrict__ x, const float* __restrict__ Wg,
    int* __restrict__ topi, float* __restrict__ topg,
    ushort_t* __restrict__ xsplit) {
  __shared__ float xl[32][260];
  __shared__ float wg[E * NE];
  __shared__ float lg[32][9];
  const int tid = threadIdx.x;
  const int t0 = blockIdx.x * 32;
  for (int r = 0; r < 32; ++r) {
    float val = x[(size_t)(t0 + r) * HD + tid];
    xl[r][tid] = val;
    unsigned short hi = f2bf(val);
    unsigned short lo = f2bf(val - bf2f(hi));
    xsplit[(size_t)(t0 + r) * 512 + tid] = hi;
    xsplit[(size_t)(t0 + r) * 512 + 256 + tid] = lo;
  }
  for (int i = tid; i < E * NE; i += 256) wg[i] = Wg[i];
  __syncthreads();
  const int r = tid >> 3, e = tid & 7;
  float acc = 0.f;
  for (int f = 0; f < E; ++f) acc += xl[r][f] * wg[f * NE + e];
  lg[r][e] = acc;
  __syncthreads();
  if (tid < 32) {
    float v[8];
#pragma unroll
    for (int j = 0; j < 8; ++j) v[j] = lg[tid][j];
    int i1 = 0; float v1 = v[0];
#pragma unroll
    for (int j = 1; j < 8; ++j) if (v[j] > v1) { v1 = v[j]; i1 = j; }
    int i2 = -1; float v2 = -1e30f;
#pragma unroll
    for (int j = 0; j < 8; ++j)
      if (j != i1 && v[j] > v2) { v2 = v[j]; i2 = j; }
    float ex = __expf(v2 - v1);
    float g1 = 1.f / (1.f + ex);
    float g2 = ex / (1.f + ex);
    int t = t0 + tid;
    topi[t * 2 + 0] = i1; topi[t * 2 + 1] = i2;
    topg[t * 2 + 0] = g1; topg[t * 2 + 1] = g2;
  }
}

// ---------------------------------------------------------------------------
// Kernel 5: build per-expert token lists. UNCHANGED.
// ---------------------------------------------------------------------------
__global__ __launch_bounds__(1024) void build_lists_kernel(
    const int* __restrict__ topi, const float* __restrict__ topg,
    int* __restrict__ list_tok, float* __restrict__ list_gate,
    int* __restrict__ counts) {
  const int e = blockIdx.x;
  const int tid = threadIdx.x;
  const int lane = tid & 63, w = tid >> 6;
  __shared__ int wsum[16];
  int running = 0;
  for (int c = 0; c < NTOK; c += 1024) {
    int t = c + tid;
    int ia = topi[t * 2 + 0], ib = topi[t * 2 + 1];
    int slot = (ia == e) ? 0 : ((ib == e) ? 1 : -1);
    int f = (slot >= 0) ? 1 : 0;
    unsigned long long m = __ballot(f);
    if (lane == 0) wsum[w] = __popcll(m);
    __syncthreads();
    int wbase = 0, total = 0;
#pragma unroll
    for (int i = 0; i < 16; ++i) {
      int s = wsum[i];
      if (i < w) wbase += s;
      total += s;
    }
    if (f) {
      int prefix = __popcll(m & ((1ull << lane) - 1ull));
      int pos = running + wbase + prefix;
      list_tok[e * NTOK + pos] = (t << 1) | slot;
      list_gate[e * NTOK + pos] = topg[t * 2 + slot];
    }
    running += total;
    __syncthreads();
  }
  if (tid == 0) counts[e] = running;
}

// ---------------------------------------------------------------------------
// Kernel 5b: expert weight 2-plane prepack (unchanged from round 6).
// ---------------------------------------------------------------------------
__global__ __launch_bounds__(256) void wsplit_kernel(
    const float* __restrict__ eW, uint4* __restrict__ Wp) {
  const int gid = blockIdx.x * 256 + threadIdx.x;
  const int lane = gid & 63;
  const int rest = gid >> 6;
  const int gct = rest & 15;
  const int kt = (rest >> 4) & 7;
  const int e = rest >> 7;
  const int kbase = kt * 32 + (lane >> 4) * 8;
  const int c = gct * 16 + (lane & 15);
  unsigned int hi[4], lo[4];
#pragma unroll
  for (int jj = 0; jj < 4; ++jj) {
    float v0 = eW[((size_t)e * HD + (kbase + 2 * jj)) * E + c];
    float v1 = eW[((size_t)e * HD + (kbase + 2 * jj + 1)) * E + c];
    unsigned short h0 = f2bf(v0), h1 = f2bf(v1);
    unsigned short l0 = f2bf(v0 - bf2f(h0)), l1 = f2bf(v1 - bf2f(h1));
    hi[jj] = (unsigned int)h0 | ((unsigned int)h1 << 16);
    lo[jj] = (unsigned int)l0 | ((unsigned int)l1 << 16);
  }
  uint4 uh, ul;
  uh.x = hi[0]; uh.y = hi[1]; uh.z = hi[2]; uh.w = hi[3];
  ul.x = lo[0]; ul.y = lo[1]; ul.z = lo[2]; ul.w = lo[3];
  Wp[(size_t)(rest * 2 + 0) * 64 + lane] = uh;
  Wp[(size_t)(rest * 2 + 1) * 64 + lane] = ul;
}

// ---------------------------------------------------------------------------
// Kernel 6: sparse expert GEMM via split-bf16 MFMA. UNCHANGED from round 6.
// ---------------------------------------------------------------------------
__global__ __launch_bounds__(256) void expert_gemm_kernel(
    const ushort_t* __restrict__ xsplit, const uint4* __restrict__ Wp,
    const float* __restrict__ eb, const int* __restrict__ list_tok,
    const float* __restrict__ list_gate, const int* __restrict__ counts,
    float* __restrict__ p0, float* __restrict__ p1) {
  int e = 0, t0 = -1;
  {
    int rem = blockIdx.x;
    for (int i = 0; i < NE; ++i) {
      int nt = (counts[i] + 31) >> 5;
      if (rem < nt) { e = i; t0 = rem * 32; break; }
      rem -= nt;
    }
  }
  if (t0 < 0) return;
  const int cnt = counts[e];
  const int nr = min(32, cnt - t0);
  __shared__ uint4 xls[32 * 65];
  __shared__ int stok[32];
  __shared__ float sg[32];
  const int tid = threadIdx.x;
  if (tid < 32) {
    int src = e * NTOK + t0 + ((tid < nr) ? tid : 0);
    stok[tid] = list_tok[src];
    sg[tid] = (tid < nr) ? list_gate[e * NTOK + t0 + tid] : 0.f;
  }
  __syncthreads();
  for (int i = tid; i < 32 * 64; i += 256) {
    int r = i >> 6, ch = i & 63;
    const uint4* src = (const uint4*)(xsplit + (size_t)(stok[r] >> 1) * 512);
    xls[r * 65 + ch] = src[ch];
  }
  __syncthreads();
  const int w = tid >> 6;
  const int lane = tid & 63;
  const int lr = lane & 15;
  const int lg4 = lane >> 4;
  f32x4 acc[2][4];
#pragma unroll
  for (int rt = 0; rt < 2; ++rt)
#pragma unroll
    for (int ct = 0; ct < 4; ++ct) acc[rt][ct] = (f32x4){0.f, 0.f, 0.f, 0.f};

  for (int kt = 0; kt < 8; ++kt) {
    short8 afrag[2][2];
#pragma unroll
    for (int rt = 0; rt < 2; ++rt)
#pragma unroll
      for (int pl = 0; pl < 2; ++pl) {
        uint4 u = xls[(rt * 16 + lr) * 65 + pl * 32 + kt * 4 + lg4];
        afrag[rt][pl] = __builtin_bit_cast(short8, u);
      }
#pragma unroll
    for (int ct = 0; ct < 4; ++ct) {
      const int gct = w * 4 + ct;
      const size_t base = (size_t)(((e * 8 + kt) * 16 + gct) * 2) * 64 + lane;
      short8 bh = __builtin_bit_cast(short8, Wp[base]);
      short8 bl = __builtin_bit_cast(short8, Wp[base + 64]);
#pragma unroll
      for (int rt = 0; rt < 2; ++rt) {
        acc[rt][ct] = __builtin_amdgcn_mfma_f32_16x16x32_bf16(
            afrag[rt][0], bh, acc[rt][ct], 0, 0, 0);
        acc[rt][ct] = __builtin_amdgcn_mfma_f32_16x16x32_bf16(
            afrag[rt][0], bl, acc[rt][ct], 0, 0, 0);
        acc[rt][ct] = __builtin_amdgcn_mfma_f32_16x16x32_bf16(
            afrag[rt][1], bh, acc[rt][ct], 0, 0, 0);
      }
    }
  }
#pragma unroll
  for (int rt = 0; rt < 2; ++rt) {
#pragma unroll
    for (int ct = 0; ct < 4; ++ct) {
      const int col = (w * 4 + ct) * 16 + lr;
      const float bias = eb[e * E + col];
#pragma unroll
      for (int reg = 0; reg < 4; ++reg) {
        const int ridx = rt * 16 + lg4 * 4 + reg;
        if (ridx < nr) {
          const int tokw = stok[ridx];
          const float g = sg[ridx];
          float* dst = ((tokw & 1) ? p1 : p0) + (size_t)(tokw >> 1) * E + col;
          *dst = g * (acc[rt][ct][reg] + bias);
        }
      }
    }
  }
}

// ---------------------------------------------------------------------------
// Kernel 7: score2 = mh @ enc^T, per batch. grid (4, 256), block 128.
// ---------------------------------------------------------------------------
__global__ __launch_bounds__(128) void score2_kernel(
    const float* __restrict__ p0, const float* __restrict__ p1,
    const float* __restrict__ enc, float* __restrict__ out) {
  const int b = blockIdx.y;
  const int pt = blockIdx.x * 25;
  __shared__ float mh[25][E];
  const int tid = threadIdx.x;
  for (int i = tid; i < 25 * E; i += 128) {
    int r = i >> 8, c = i & 255;
    int t = b * P + pt + r;
    mh[r][c] = p0[(size_t)t * E + c] + p1[(size_t)t * E + c];
  }
  __syncthreads();
  const int n = tid;
  if (n >= N1) return;
  float acc[25];
#pragma unroll
  for (int r = 0; r < 25; ++r) acc[r] = 0.f;
  const float* er = enc + ((size_t)b * N1 + n) * E;
  for (int ee = 0; ee < E; ee += 4) {
    float4 ev = *(const float4*)&er[ee];
#pragma unroll
    for (int r = 0; r < 25; ++r) {
      float4 mv = *(const float4*)&mh[r][ee];
      acc[r] += mv.x * ev.x + mv.y * ev.y + mv.z * ev.z + mv.w * ev.w;
    }
  }
#pragma unroll
  for (int r = 0; r < 25; ++r) out[((size_t)b * P + pt + r) * N1 + n] = acc[r];
}

// ---------------------------------------------------------------------------
// Kernel 8: add biases, tanh clip, + ninf, row softmax.  In-place on d_out.
// ---------------------------------------------------------------------------
__global__ __launch_bounds__(256) void softmax2_kernel(
    float* __restrict__ sc, const float* __restrict__ ab,
    const float* __restrict__ ab1, const float* __restrict__ ninf) {
  const int row = blockIdx.x * 4 + (threadIdx.x >> 6);
  const int lane = threadIdx.x & 63;
  float* srow = sc + (size_t)row * N1;
  const float* a = ab + (size_t)row * N1;
  const float* a1 = ab1 + (size_t)row * N1;
  const float* nf = ninf + (size_t)row * N1;
  float s0 = -1e30f, s1 = -1e30f;
  {
    int i = lane;
    float s = srow[i] + a[i] + a1[i];
    float e2 = __expf(s * 0.125f);
    float th = 1.f - 2.f / (e2 + 1.f);
    s0 = 10.f * th + nf[i];
  }
  if (lane < N1 - 64) {
    int i = lane + 64;
    float s = srow[i] + a[i] + a1[i];
    float e2 = __expf(s * 0.125f);
    float th = 1.f - 2.f / (e2 + 1.f);
    s1 = 10.f * th + nf[i];
  }
  float mx = fmaxf(s0, s1);
#pragma unroll
  for (int off = 32; off > 0; off >>= 1) mx = fmaxf(mx, __shfl_xor(mx, off, 64));
  float p0 = __expf(s0 - mx);
  float p1 = (lane < N1 - 64) ? __expf(s1 - mx) : 0.f;
  float sum = p0 + p1;
#pragma unroll
  for (int off = 32; off > 0; off >>= 1) sum += __shfl_xor(sum, off, 64);
  float inv = 1.f / sum;
  srow[lane] = p0 * inv;
  if (lane < N1 - 64) srow[lane + 64] = p1 * inv;
}

// ---------------------------------------------------------------------------
extern "C" void kernel_launch(void* const* d_in, const int* in_sizes, int n_in,
                              void* d_out, int out_size, void* d_ws,
                              size_t ws_size, hipStream_t stream) {
  const float* eln  = (const float*)d_in[0];
  const float* attr = (const float*)d_in[1];
  const float* enc  = (const float*)d_in[2];
  const float* ninf = (const float*)d_in[3];
  const float* ab   = (const float*)d_in[4];
  const float* ab1  = (const float*)d_in[5];
  const float* Wq   = (const float*)d_in[6];
  const float* Wk   = (const float*)d_in[7];
  const float* Wv   = (const float*)d_in[8];
  const float* Wg   = (const float*)d_in[9];
  const float* eW   = (const float*)d_in[10];
  const float* eb   = (const float*)d_in[11];
  float* out = (float*)d_out;

  char* ws = (char*)d_ws;
  size_t off = 0;
  auto carve = [&](size_t bytes) {
    char* p = ws + off;
    off += (bytes + 255) & ~size_t(255);
    return p;
  };
  float* kbuf = (float*)carve(sizeof(float) * NKV * HD);
  float* vbuf = (float*)carve(sizeof(float) * NKV * HD);
  float* qbuf = (float*)carve(sizeof(float) * NTOK * HD);
  float* xbuf = (float*)carve(sizeof(float) * NTOK * HD);
  int*   topi = (int*)carve(sizeof(int) * NTOK * 2);
  float* topg = (float*)carve(sizeof(float) * NTOK * 2);
  int*   counts = (int*)carve(sizeof(int) * 16);
  int*   list_tok = (int*)carve(sizeof(int) * NE * NTOK);
  float* list_gate = (float*)carve(sizeof(float) * NE * NTOK);
  uint4* Wp  = (uint4*)carve(sizeof(ushort_t) * NE * HD * E * 2);  // 2 MB
  uint4* Wk3 = (uint4*)carve((size_t)8 * 16 * 3 * 64 * 16);        // 393 KB
  uint4* Wv3 = (uint4*)carve((size_t)8 * 16 * 3 * 64 * 16);
  uint4* Wq3 = (uint4*)carve((size_t)9 * 16 * 3 * 64 * 16);        // 442 KB
  float* pp0 = kbuf;
  float* pp1 = vbuf;
  ushort_t* xsplit = (ushort_t*)qbuf;

  wsplit_kernel<<<256, 256, 0, stream>>>(eW, Wp);
  wsplit3_kernel<<<32, 256, 0, stream>>>(Wk, Wk3, 256);
  wsplit3_kernel<<<32, 256, 0, stream>>>(Wv, Wv3, 256);
  wsplit3_kernel<<<36, 256, 0, stream>>>(Wq, Wq3, 260);
  proj3_kernel<8, 0><<<NKV / 32, 256, 0, stream>>>(enc, nullptr, Wk3, kbuf);
  proj3_kernel<8, 0><<<NKV / 32, 256, 0, stream>>>(enc, nullptr, Wv3, vbuf);
  proj3_kernel<9, 1><<<NTOK / 32, 256, 0, stream>>>(eln, attr, Wq3, qbuf);
  attn_kernel<<<B * 4, 256, 0, stream>>>(qbuf, kbuf, vbuf, ninf, xbuf);
  logits_top2_kernel<<<NTOK / 32, 256, 0, stream>>>(xbuf, Wg, topi, topg,
                                                    xsplit);
  build_lists_kernel<<<NE, 1024, 0, stream>>>(topi, topg, list_tok, list_gate,
                                              counts);
  expert_gemm_kernel<<<1608, 256, 0, stream>>>(xsplit, Wp, eb, list_tok,
                                               list_gate, counts, pp0, pp1);
  dim3 s2(4, B);
  score2_kernel<<<s2, 128, 0, stream>>>(pp0, pp1, enc, out);
  softmax2_kernel<<<NTOK / 4, 256, 0, stream>>>(out, ab, ab1, ninf);
}